// Round 1
// baseline (33001.111 us; speedup 1.0000x reference)
//
#include <hip/hip_runtime.h>
#include <cstdint>
#include <cstddef>

// ---- model constants ----
#define B_    16
#define S_    256
#define H_    384
#define H2_   1536
#define NH_   2
#define DH_   192      // H/NH
#define TOUT_ 1024
#define MEL_  80
#define L_    4

// ---- gemm epilogue flags ----
#define F_BIAS  1
#define F_ACCUM 2
#define F_RELU  4
#define F_RES   8
#define F_TRANS 16

// sinusoidal positional encoding value for (t, i)
__device__ __forceinline__ float pe_val(int t, int i) {
  int j = i >> 1;
  float den = expf(-9.210340371976184f * (float)(2 * j) / (float)H_); // ln(10000)
  float ang = (float)t * den;
  return (i & 1) ? cosf(ang) : sinf(ang);
}

// ---- embedding + posenc: out[b,t,:] = emb[tok]*sqrt(H) + pe(t,:) ----
__global__ void embed_kernel(const int* __restrict__ tokens,
                             const float* __restrict__ emb,
                             float* __restrict__ out) {
  int bs = blockIdx.x;               // 0 .. B*S-1
  int t  = bs & (S_ - 1);
  int tok = tokens[bs];
  const float* e = emb + (size_t)tok * H_;
  float* o = out + (size_t)bs * H_;
  for (int i = threadIdx.x; i < H_; i += blockDim.x)
    o[i] = e[i] * 19.595917942265423f + pe_val(t, i);   // sqrt(384)
}

// ---- generic tiled fp32 GEMM: C[M,N] (+)= shiftA(A)[M,Kd] @ W[Kd,N] with epilogue ----
// A rows are time-shifted within each batch of length T when shift != 0 (conv taps).
__global__ __launch_bounds__(256) void gemm_kernel(
    const float* __restrict__ A, const float* __restrict__ W,
    const float* __restrict__ bias, const float* __restrict__ res,
    float* __restrict__ C,
    int M, int N, int Kd, int T, int shift, int flags)
{
  __shared__ float As[16][68];   // [k][m], padded for b128 alignment
  __shared__ float Bs[16][68];   // [k][n]
  const int tid = threadIdx.x;
  const int tx = tid & 15, ty = tid >> 4;
  const int bm = blockIdx.y * 64, bn = blockIdx.x * 64;

  // A-load mapping: element e = tid*4 .. +3 -> row r=e/16, k-col c=e%16
  int ea = tid * 4;
  int ar = ea >> 4, ac = ea & 15;
  int am = bm + ar;
  int arow; bool avalid;
  if (shift == 0) { arow = am; avalid = (am < M); }
  else {
    int b = am / T, t = am - b * T;
    int ts = t + shift;
    avalid = (am < M) && (ts >= 0) && (ts < T);
    arow = b * T + ts;
  }
  // W-load mapping: element e -> k=e/64, n=e%64
  int eb = tid * 4;
  int bk = eb >> 6, bnn = eb & 63;
  int gn = bn + bnn;

  float acc[4][4] = {};

  for (int k0 = 0; k0 < Kd; k0 += 16) {
    float4 av = make_float4(0.f, 0.f, 0.f, 0.f);
    if (avalid) av = *(const float4*)(A + (size_t)arow * Kd + k0 + ac);
    float4 wv = make_float4(0.f, 0.f, 0.f, 0.f);
    {
      const float* wp = W + (size_t)(k0 + bk) * N + gn;
      if (gn + 3 < N) wv = *(const float4*)wp;
      else {
        if (gn + 0 < N) wv.x = wp[0];
        if (gn + 1 < N) wv.y = wp[1];
        if (gn + 2 < N) wv.z = wp[2];
        if (gn + 3 < N) wv.w = wp[3];
      }
    }
    As[ac + 0][ar] = av.x; As[ac + 1][ar] = av.y;
    As[ac + 2][ar] = av.z; As[ac + 3][ar] = av.w;
    Bs[bk][bnn + 0] = wv.x; Bs[bk][bnn + 1] = wv.y;
    Bs[bk][bnn + 2] = wv.z; Bs[bk][bnn + 3] = wv.w;
    __syncthreads();
#pragma unroll
    for (int kk = 0; kk < 16; ++kk) {
      float a0 = As[kk][ty * 4 + 0], a1 = As[kk][ty * 4 + 1];
      float a2 = As[kk][ty * 4 + 2], a3 = As[kk][ty * 4 + 3];
      float b0 = Bs[kk][tx * 4 + 0], b1 = Bs[kk][tx * 4 + 1];
      float b2 = Bs[kk][tx * 4 + 2], b3 = Bs[kk][tx * 4 + 3];
      acc[0][0] += a0 * b0; acc[0][1] += a0 * b1; acc[0][2] += a0 * b2; acc[0][3] += a0 * b3;
      acc[1][0] += a1 * b0; acc[1][1] += a1 * b1; acc[1][2] += a1 * b2; acc[1][3] += a1 * b3;
      acc[2][0] += a2 * b0; acc[2][1] += a2 * b1; acc[2][2] += a2 * b2; acc[2][3] += a2 * b3;
      acc[3][0] += a3 * b0; acc[3][1] += a3 * b1; acc[3][2] += a3 * b2; acc[3][3] += a3 * b3;
    }
    __syncthreads();
  }

#pragma unroll
  for (int i = 0; i < 4; ++i) {
    int m = bm + ty * 4 + i;
    if (m >= M) continue;
#pragma unroll
    for (int j = 0; j < 4; ++j) {
      int n = bn + tx * 4 + j;
      if (n >= N) continue;
      float v = acc[i][j];
      if (flags & F_BIAS) v += bias[n];
      size_t idx = (size_t)m * N + n;
      if (flags & F_ACCUM) v += C[idx];
      if (flags & F_RES)   v += res[idx];
      if (flags & F_RELU)  v = fmaxf(v, 0.f);
      if (flags & F_TRANS) {
        int b = m / T, t = m - b * T;
        C[((size_t)(b * MEL_ + n)) * TOUT_ + t] = v;
      } else {
        C[idx] = v;
      }
    }
  }
}

// ---- attention: per (b, head, 8-query tile); scores live in LDS; O written into Q buffer ----
__global__ __launch_bounds__(256) void attn_kernel(
    const float* __restrict__ Q, const float* __restrict__ K,
    const float* __restrict__ V, float* __restrict__ O, int Tlen)
{
  __shared__ float qs[8 * DH_];     // 6 KB
  __shared__ float kv[16 * DH_];    // 12 KB (reused for K then V chunks)
  __shared__ float sc[8 * 1024];    // 32 KB (scores, stride Tlen)
  const int tid = threadIdx.x;
  const int q0 = blockIdx.x * 8;
  const int h  = blockIdx.y;
  const int b  = blockIdx.z;
  const size_t rowbase = (size_t)b * Tlen;
  const int hoff = h * DH_;

  // load + pre-scale Q tile (fold 1/sqrt(dh))
  for (int e = tid; e < 8 * DH_; e += 256) {
    int qi = e / DH_, d = e - qi * DH_;
    qs[e] = Q[(rowbase + q0 + qi) * H_ + hoff + d] * 0.07216878364870323f;
  }
  // scores
  for (int kc = 0; kc < Tlen; kc += 16) {
    __syncthreads();
    for (int e = tid; e < 16 * DH_; e += 256) {
      int ki = e / DH_, d = e - ki * DH_;
      kv[e] = K[(rowbase + kc + ki) * H_ + hoff + d];
    }
    __syncthreads();
    if (tid < 128) {
      int qi = tid >> 4, ki = tid & 15;
      const float* qp = qs + qi * DH_;
      const float* kp = kv + ki * DH_;
      float s = 0.f;
      for (int d = 0; d < DH_; ++d) s += qp[d] * kp[d];
      sc[qi * Tlen + kc + ki] = s;
    }
  }
  __syncthreads();
  // softmax: 8 rows x 32 lanes
  {
    int row = tid >> 5, lane = tid & 31;
    float* sp = sc + row * Tlen;
    float m = -1e30f;
    for (int k2 = lane; k2 < Tlen; k2 += 32) m = fmaxf(m, sp[k2]);
#pragma unroll
    for (int o = 16; o; o >>= 1) m = fmaxf(m, __shfl_down(m, o, 32));
    m = __shfl(m, 0, 32);
    float l = 0.f;
    for (int k2 = lane; k2 < Tlen; k2 += 32) l += expf(sp[k2] - m);
#pragma unroll
    for (int o = 16; o; o >>= 1) l += __shfl_down(l, o, 32);
    l = __shfl(l, 0, 32);
    float inv = 1.0f / l;
    for (int k2 = lane; k2 < Tlen; k2 += 32) sp[k2] = expf(sp[k2] - m) * inv;
  }
  // P @ V : each thread owns 6 (qi, d) outputs
  float oa[6] = {0.f, 0.f, 0.f, 0.f, 0.f, 0.f};
  for (int vc = 0; vc < Tlen; vc += 16) {
    __syncthreads();
    for (int e = tid; e < 16 * DH_; e += 256) {
      int ki = e / DH_, d = e - ki * DH_;
      kv[e] = V[(rowbase + vc + ki) * H_ + hoff + d];
    }
    __syncthreads();
#pragma unroll
    for (int i = 0; i < 6; ++i) {
      int e = tid + i * 256;
      int qi = e / DH_, d = e - qi * DH_;
      const float* sp = sc + qi * Tlen + vc;
      const float* vp = kv + d;
      float a = oa[i];
#pragma unroll
      for (int ki = 0; ki < 16; ++ki) a += sp[ki] * vp[ki * DH_];
      oa[i] = a;
    }
  }
#pragma unroll
  for (int i = 0; i < 6; ++i) {
    int e = tid + i * 256;
    int qi = e / DH_, d = e - qi * DH_;
    O[(rowbase + q0 + qi) * H_ + hoff + d] = oa[i];
  }
}

// ---- LayerNorm over last dim H=384, one wave per row; sb: [0..H) scale, [H..2H) bias ----
__global__ __launch_bounds__(256) void ln_kernel(
    const float* __restrict__ X, const float* __restrict__ sb,
    float* __restrict__ Y, int M)
{
  int row  = blockIdx.x * 4 + (threadIdx.x >> 6);
  int lane = threadIdx.x & 63;
  const float* x = X + (size_t)row * H_;
  float v[6]; float s = 0.f, ss = 0.f;
#pragma unroll
  for (int i = 0; i < 6; ++i) {
    v[i] = x[lane + i * 64];
    s += v[i]; ss += v[i] * v[i];
  }
#pragma unroll
  for (int o = 32; o; o >>= 1) { s += __shfl_down(s, o, 64); ss += __shfl_down(ss, o, 64); }
  s = __shfl(s, 0, 64); ss = __shfl(ss, 0, 64);
  float mean = s * (1.0f / H_);
  float var  = ss * (1.0f / H_) - mean * mean;
  float r = rsqrtf(var + 1e-5f);
  float* y = Y + (size_t)row * H_;
#pragma unroll
  for (int i = 0; i < 6; ++i) {
    int c = lane + i * 64;
    y[c] = (v[i] - mean) * r * sb[c] + sb[H_ + c];
  }
}

// ---- GEMV N=1 for length predictor ----
__global__ void gemv_kernel(const float* __restrict__ A, const float* __restrict__ w,
                            const float* __restrict__ bflt, float* __restrict__ out, int M)
{
  int row  = blockIdx.x * 4 + (threadIdx.x >> 6);
  int lane = threadIdx.x & 63;
  const float* a = A + (size_t)row * H_;
  float s = 0.f;
#pragma unroll
  for (int i = 0; i < 6; ++i) s += a[lane + i * 64] * w[lane + i * 64];
#pragma unroll
  for (int o = 32; o; o >>= 1) s += __shfl_down(s, o, 64);
  if (lane == 0) out[row] = s + bflt[0];
}

// ---- per-batch inclusive cumsum of durations ----
__global__ void cumsum_kernel(const int* __restrict__ al, int* __restrict__ cum) {
  int b = threadIdx.x;
  if (b < B_) {
    int acc = 0;
    for (int s = 0; s < S_; ++s) { acc += al[b * S_ + s]; cum[b * S_ + s] = acc; }
  }
}

// ---- length regulator (searchsorted-right) + posenc, fused ----
__global__ void expand_kernel(const float* __restrict__ xe, const int* __restrict__ cum,
                              float* __restrict__ y) {
  int t = blockIdx.x;     // 0..TOUT-1
  int b = blockIdx.y;
  const int* c = cum + b * S_;
  int lo = 0, hi = S_;
  while (lo < hi) { int mid = (lo + hi) >> 1; if (c[mid] <= t) lo = mid + 1; else hi = mid; }
  int idx = lo < S_ ? lo : S_ - 1;
  bool valid = t < c[S_ - 1];
  const float* src = xe + ((size_t)b * S_ + idx) * H_;
  float* dst = y + ((size_t)b * TOUT_ + t) * H_;
  for (int i = threadIdx.x; i < H_; i += blockDim.x)
    dst[i] = (valid ? src[i] : 0.f) + pe_val(t, i);
}

// ================= host-side orchestration =================
static inline void gemm(const float* A, const float* W, const float* bias, const float* res,
                        float* C, int M, int N, int Kd, int T, int shift, int flags,
                        hipStream_t st)
{
  dim3 grid((N + 63) / 64, (M + 63) / 64);
  hipLaunchKernelGGL(gemm_kernel, grid, dim3(256), 0, st, A, W, bias, res, C,
                     M, N, Kd, T, shift, flags);
}

static void fft_block(float* x, float* y, float* q, float* k, float* v, float* h2,
                      const float* aw, const float* ab,
                      const float* c1w, const float* c1b,
                      const float* c2w, const float* c2b,
                      const float* ln, int T, hipStream_t st)
{
  int M = B_ * T;
  // QKV projections
  gemm(x, aw + 0 * H_ * H_, ab + 0 * H_, nullptr, q, M, H_, H_, T, 0, F_BIAS, st);
  gemm(x, aw + 1 * H_ * H_, ab + 1 * H_, nullptr, k, M, H_, H_, T, 0, F_BIAS, st);
  gemm(x, aw + 2 * H_ * H_, ab + 2 * H_, nullptr, v, M, H_, H_, T, 0, F_BIAS, st);
  // attention (O written back into q buffer — safe: each wg only reads its own q rows)
  hipLaunchKernelGGL(attn_kernel, dim3(T / 8, NH_, B_), dim3(256), 0, st, q, k, v, q, T);
  // output projection + residual
  gemm(q, aw + 3 * H_ * H_, ab + 3 * H_, x, y, M, H_, H_, T, 0, F_BIAS | F_RES, st);
  hipLaunchKernelGGL(ln_kernel, dim3(M / 4), dim3(256), 0, st, y, ln + 0, x, M);
  // conv1 (H -> H2), K=3 as 3 shifted GEMMs, ReLU at the end
  gemm(x, c1w + 0 * (size_t)H_ * H2_, c1b, nullptr, h2, M, H2_, H_, T, -1, F_BIAS, st);
  gemm(x, c1w + 1 * (size_t)H_ * H2_, c1b, nullptr, h2, M, H2_, H_, T,  0, F_ACCUM, st);
  gemm(x, c1w + 2 * (size_t)H_ * H2_, c1b, nullptr, h2, M, H2_, H_, T, +1, F_ACCUM | F_RELU, st);
  // conv2 (H2 -> H) + residual x
  gemm(h2, c2w + 0 * (size_t)H2_ * H_, c2b, nullptr, y, M, H_, H2_, T, -1, F_BIAS, st);
  gemm(h2, c2w + 1 * (size_t)H2_ * H_, c2b, nullptr, y, M, H_, H2_, T,  0, F_ACCUM, st);
  gemm(h2, c2w + 2 * (size_t)H2_ * H_, c2b, x,       y, M, H_, H2_, T, +1, F_ACCUM | F_RES, st);
  hipLaunchKernelGGL(ln_kernel, dim3(M / 4), dim3(256), 0, st, y, ln + 2 * H_, x, M);
}

extern "C" void kernel_launch(void* const* d_in, const int* in_sizes, int n_in,
                              void* d_out, int out_size, void* d_ws, size_t ws_size,
                              hipStream_t stream)
{
  (void)in_sizes; (void)n_in; (void)out_size; (void)ws_size;
  const int*   tokens      = (const int*)d_in[0];
  const int*   alignes     = (const int*)d_in[1];
  const float* tok_emb     = (const float*)d_in[2];
  const float* enc_attn_w  = (const float*)d_in[3];
  const float* enc_attn_b  = (const float*)d_in[4];
  const float* enc_conv1_w = (const float*)d_in[5];
  const float* enc_conv1_b = (const float*)d_in[6];
  const float* enc_conv2_w = (const float*)d_in[7];
  const float* enc_conv2_b = (const float*)d_in[8];
  const float* enc_ln      = (const float*)d_in[9];
  const float* dec_attn_w  = (const float*)d_in[10];
  const float* dec_attn_b  = (const float*)d_in[11];
  const float* dec_conv1_w = (const float*)d_in[12];
  const float* dec_conv1_b = (const float*)d_in[13];
  const float* dec_conv2_w = (const float*)d_in[14];
  const float* dec_conv2_b = (const float*)d_in[15];
  const float* dec_ln      = (const float*)d_in[16];
  const float* al_c1w      = (const float*)d_in[17];
  const float* al_c1b      = (const float*)d_in[18];
  const float* al_c2w      = (const float*)d_in[19];
  const float* al_c2b      = (const float*)d_in[20];
  const float* al_ln       = (const float*)d_in[21];
  const float* al_lin_w    = (const float*)d_in[22];
  const float* al_lin_b    = (const float*)d_in[23];
  const float* dec_lin_w   = (const float*)d_in[24];
  const float* dec_lin_b   = (const float*)d_in[25];

  // workspace layout (floats)
  float* ws = (float*)d_ws;
  size_t off = 0;
  const size_t MD = (size_t)B_ * TOUT_;        // 16384 max rows
  float* bufX  = ws + off; off += MD * H_;
  float* bufY  = ws + off; off += MD * H_;
  float* bufQ  = ws + off; off += MD * H_;
  float* bufK  = ws + off; off += MD * H_;
  float* bufV  = ws + off; off += MD * H_;
  float* bufH2 = ws + off; off += MD * H2_;
  float* xenc  = ws + off; off += (size_t)B_ * S_ * H_;
  int*   cum   = (int*)(ws + off);

  float* mel_out = (float*)d_out;
  float* len_out = mel_out + (size_t)B_ * MEL_ * TOUT_;

  // ---- Encoder ----
  hipLaunchKernelGGL(embed_kernel, dim3(B_ * S_), dim3(128), 0, stream, tokens, tok_emb, bufX);
  for (int i = 0; i < L_; ++i)
    fft_block(bufX, bufY, bufQ, bufK, bufV, bufH2,
              enc_attn_w + (size_t)i * 4 * H_ * H_, enc_attn_b + (size_t)i * 4 * H_,
              enc_conv1_w + (size_t)i * 3 * H_ * H2_, enc_conv1_b + (size_t)i * H2_,
              enc_conv2_w + (size_t)i * 3 * H2_ * H_, enc_conv2_b + (size_t)i * H_,
              enc_ln + (size_t)i * 4 * H_, S_, stream);
  // keep encoder output (expand must not alias bufX)
  hipMemcpyAsync(xenc, bufX, (size_t)B_ * S_ * H_ * sizeof(float),
                 hipMemcpyDeviceToDevice, stream);

  // ---- Aligner (duration predictor) ----
  {
    int Ma = B_ * S_;
    gemm(xenc, al_c1w + 0 * H_ * H_, al_c1b, nullptr, bufQ, Ma, H_, H_, S_, -1, F_BIAS, stream);
    gemm(xenc, al_c1w + 1 * H_ * H_, al_c1b, nullptr, bufQ, Ma, H_, H_, S_,  0, F_ACCUM, stream);
    gemm(xenc, al_c1w + 2 * H_ * H_, al_c1b, nullptr, bufQ, Ma, H_, H_, S_, +1, F_ACCUM | F_RELU, stream);
    hipLaunchKernelGGL(ln_kernel, dim3(Ma / 4), dim3(256), 0, stream, bufQ, al_ln + 0, bufY, Ma);
    gemm(bufY, al_c2w + 0 * H_ * H_, al_c2b, nullptr, bufQ, Ma, H_, H_, S_, -1, F_BIAS, stream);
    gemm(bufY, al_c2w + 1 * H_ * H_, al_c2b, nullptr, bufQ, Ma, H_, H_, S_,  0, F_ACCUM, stream);
    gemm(bufY, al_c2w + 2 * H_ * H_, al_c2b, nullptr, bufQ, Ma, H_, H_, S_, +1, F_ACCUM | F_RELU, stream);
    hipLaunchKernelGGL(ln_kernel, dim3(Ma / 4), dim3(256), 0, stream, bufQ, al_ln + 2 * H_, bufY, Ma);
    hipLaunchKernelGGL(gemv_kernel, dim3(Ma / 4), dim3(256), 0, stream,
                       bufY, al_lin_w, al_lin_b, len_out, Ma);
  }

  // ---- Length regulator + decoder posenc ----
  hipLaunchKernelGGL(cumsum_kernel, dim3(1), dim3(64), 0, stream, alignes, cum);
  hipLaunchKernelGGL(expand_kernel, dim3(TOUT_, B_), dim3(128), 0, stream, xenc, cum, bufX);

  // ---- Decoder ----
  for (int i = 0; i < L_; ++i)
    fft_block(bufX, bufY, bufQ, bufK, bufV, bufH2,
              dec_attn_w + (size_t)i * 4 * H_ * H_, dec_attn_b + (size_t)i * 4 * H_,
              dec_conv1_w + (size_t)i * 3 * H_ * H2_, dec_conv1_b + (size_t)i * H2_,
              dec_conv2_w + (size_t)i * 3 * H2_ * H_, dec_conv2_b + (size_t)i * H_,
              dec_ln + (size_t)i * 4 * H_, TOUT_, stream);

  // ---- Final mel projection, written transposed to [B, MEL, TOUT] ----
  gemm(bufX, dec_lin_w, dec_lin_b, nullptr, mel_out,
       B_ * TOUT_, MEL_, H_, TOUT_, 0, F_BIAS | F_TRANS, stream);
}

// Round 2
// 4060.057 us; speedup vs baseline: 8.1282x; 8.1282x over previous
//
#include <hip/hip_runtime.h>
#include <cstdint>
#include <cstddef>

// ---- model constants ----
#define B_    16
#define S_    256
#define H_    384
#define H2_   1536
#define NH_   2
#define DH_   192
#define TOUT_ 1024
#define MEL_  80
#define L_    4

// ---- gemm epilogue flags ----
#define F_BIAS  1
#define F_RES   2
#define F_RELU  4
#define F_STF   8
#define F_STB   16
#define F_TRANS 32

typedef __attribute__((ext_vector_type(8))) short short8;
typedef __attribute__((ext_vector_type(4))) float floatx4;

// fp32 -> bf16 bits, round-to-nearest-even
__device__ __forceinline__ short f2b(float f) {
  union { float f; unsigned u; } v; v.f = f;
  unsigned r = (v.u + 0x7fffu + ((v.u >> 16) & 1u)) >> 16;
  return (short)r;
}

__device__ __forceinline__ float pe_val(int t, int i) {
  int j = i >> 1;
  float den = __expf(-9.210340371976184f * (float)(2 * j) / (float)H_);
  float ang = (float)t * den;
  return (i & 1) ? __cosf(ang) : __sinf(ang);
}

// ============ weight prep ============
// transpose fp32 [K][N] -> bf16 [N][K]; matrices indexed by blockIdx.z over two groups
__global__ __launch_bounds__(256) void wtrans_kernel(const float* __restrict__ sa,
                                                     const float* __restrict__ sb,
                                                     int na, int K, int N,
                                                     short* __restrict__ dst) {
  __shared__ float t[32][33];
  int id = blockIdx.z;
  const float* s = (id < na) ? sa + (size_t)id * K * N : sb + (size_t)(id - na) * K * N;
  short* o = dst + (size_t)id * K * N;
  int n0 = blockIdx.x * 32, k0 = blockIdx.y * 32;
  int tx = threadIdx.x & 31, ty = threadIdx.x >> 5;
#pragma unroll
  for (int i = 0; i < 4; ++i)
    t[ty + i * 8][tx] = s[(size_t)(k0 + ty + i * 8) * N + n0 + tx];
  __syncthreads();
#pragma unroll
  for (int i = 0; i < 4; ++i)
    o[(size_t)(n0 + ty + i * 8) * K + k0 + tx] = f2b(t[tx][ty + i * 8]);
}

// mel weight [384][80] -> bf16 [128][384] (rows >= 80 zero)
__global__ void melpad_kernel(const float* __restrict__ w, short* __restrict__ dst) {
  int i = blockIdx.x * 256 + threadIdx.x;     // 128*384
  int n = i / H_, k = i - n * H_;
  dst[i] = (n < MEL_) ? f2b(w[(size_t)k * MEL_ + n]) : (short)0;
}

// ============ embedding + posenc ============
__global__ void embed_kernel(const int* __restrict__ tokens, const float* __restrict__ emb,
                             float* __restrict__ xf, short* __restrict__ xb) {
  int bs = blockIdx.x;
  int t  = bs & (S_ - 1);
  int tok = tokens[bs];
  const float* e = emb + (size_t)tok * H_;
  float* of = xf + (size_t)bs * H_;
  short* ob = xb + (size_t)bs * H_;
  for (int i = threadIdx.x; i < H_; i += blockDim.x) {
    float v = e[i] * 19.595917942265423f + pe_val(t, i);
    of[i] = v; ob[i] = f2b(v);
  }
}

// ============ bf16 MFMA GEMM ============
// C[M,N] = sum_tap shift(A)[M,K] @ W[tap][K,N]; Wt is [ntaps][N][K] bf16 (k-contig)
__global__ __launch_bounds__(256) void mfma_gemm(
    const short* __restrict__ A, const short* __restrict__ Wt,
    const float* __restrict__ bias, const float* __restrict__ res,
    float* __restrict__ Cf, short* __restrict__ Cb,
    int M, int N, int Kd, int T, int ntaps, int Nout, int flags)
{
  __shared__ __align__(16) short As[128 * 40];   // rows padded 32->40 halfwords
  __shared__ __align__(16) short Bs[128 * 40];
  const int tid = threadIdx.x;
  const int wave = tid >> 6, lane = tid & 63, quad = lane >> 4, lm = lane & 15;
  const int bm = blockIdx.y * 128, bn = blockIdx.x * 128;
  const int wm = (wave >> 1) * 64, wn = (wave & 1) * 64;
  const int b0 = bm / T, t0 = bm - b0 * T;     // 128 | T, block never crosses batch
  floatx4 acc[4][4] = {};

  for (int tap = 0; tap < ntaps; ++tap) {
    const int shift = tap - (ntaps >> 1);
    const short* Wp = Wt + (size_t)tap * N * Kd + (size_t)bn * Kd;
    for (int k0 = 0; k0 < Kd; k0 += 32) {
#pragma unroll
      for (int i = 0; i < 2; ++i) {
        int u = tid + i * 256;
        int r = u >> 2, ko = (u & 3) * 8;
        int t = t0 + r + shift;
        short8 av{};
        if (t >= 0 && t < T)
          av = *(const short8*)(A + (size_t)(b0 * T + t) * Kd + k0 + ko);
        *(short8*)(&As[r * 40 + ko]) = av;
        short8 wv = *(const short8*)(Wp + (size_t)r * Kd + k0 + ko);
        *(short8*)(&Bs[r * 40 + ko]) = wv;
      }
      __syncthreads();
      short8 af[4], bfr[4];
#pragma unroll
      for (int mt = 0; mt < 4; ++mt)
        af[mt] = *(const short8*)(&As[(wm + mt * 16 + lm) * 40 + quad * 8]);
#pragma unroll
      for (int nt = 0; nt < 4; ++nt)
        bfr[nt] = *(const short8*)(&Bs[(wn + nt * 16 + lm) * 40 + quad * 8]);
#pragma unroll
      for (int mt = 0; mt < 4; ++mt)
#pragma unroll
        for (int nt = 0; nt < 4; ++nt)
          acc[mt][nt] = __builtin_amdgcn_mfma_f32_16x16x32_bf16(af[mt], bfr[nt],
                                                                acc[mt][nt], 0, 0, 0);
      __syncthreads();
    }
  }

#pragma unroll
  for (int mt = 0; mt < 4; ++mt) {
#pragma unroll
    for (int r2 = 0; r2 < 4; ++r2) {
      int gm = bm + wm + mt * 16 + quad * 4 + r2;
#pragma unroll
      for (int nt = 0; nt < 4; ++nt) {
        int gn = bn + wn + nt * 16 + lm;
        float v = acc[mt][nt][r2];
        if (flags & F_TRANS) {
          if (gn < Nout) {
            if (flags & F_BIAS) v += bias[gn];
            int bb = gm / T, tt = gm - bb * T;
            Cf[((size_t)bb * Nout + gn) * T + tt] = v;
          }
          continue;
        }
        if (flags & F_BIAS) v += bias[gn];
        size_t idx = (size_t)gm * N + gn;
        if (flags & F_RES) v += res[idx];
        if (flags & F_RELU) v = fmaxf(v, 0.f);
        if (flags & F_STF) Cf[idx] = v;
        if (flags & F_STB) Cb[idx] = f2b(v);
      }
    }
  }
}

// ============ V transpose: QKV cols 768..1151 -> Vt[b][h][d][T] ============
__global__ __launch_bounds__(256) void vtrans_kernel(const short* __restrict__ qkv,
                                                     short* __restrict__ vt, int T) {
  __shared__ short tile[32][34];
  int b = blockIdx.z, d0 = blockIdx.y * 32, t0 = blockIdx.x * 32;
  int tx = threadIdx.x & 31, ty = threadIdx.x >> 5;
#pragma unroll
  for (int i = 0; i < 4; ++i)
    tile[ty + i * 8][tx] = qkv[(size_t)(b * T + t0 + ty + i * 8) * 1152 + 768 + d0 + tx];
  __syncthreads();
  int h = (d0 >= DH_) ? 1 : 0;
  int dd0 = d0 - h * DH_;
#pragma unroll
  for (int i = 0; i < 4; ++i)
    vt[((size_t)((b * NH_ + h) * DH_) + dd0 + ty + i * 8) * T + t0 + tx] = tile[tx][ty + i * 8];
}

// ============ MFMA attention: one block per (b, h, 16-query tile) ============
#define SCW 1028
__global__ __launch_bounds__(256) void attn_mfma(const short* __restrict__ qkv,
                                                 const short* __restrict__ vt,
                                                 short* __restrict__ o, int T)
{
  __shared__ __align__(16) float sc[16 * SCW];   // 65792 B
  __shared__ __align__(16) short qs[16 * 200];   // rows padded 192->200
  __shared__ float invl[16];
  const int tid = threadIdx.x;
  const int wave = tid >> 6, lane = tid & 63, quad = lane >> 4, lm = lane & 15;
  const int q0 = blockIdx.x * 16, h = blockIdx.y, b = blockIdx.z;
  const short* qb = qkv + (size_t)b * T * 1152 + (size_t)h * DH_;
  const short* kb = qb + 384;
  const short* vb = vt + (size_t)(b * NH_ + h) * DH_ * T;

  for (int u = tid; u < 16 * 24; u += 256) {
    int r = u / 24, c = u - r * 24;
    *(int4*)(qs + r * 200 + c * 8) = *(const int4*)(qb + (size_t)(q0 + r) * 1152 + c * 8);
  }
  __syncthreads();

  // scores: S[q][k] via MFMA over d (K=192 = 6*32)
  const int nkt = T >> 4;
  for (int kt = wave; kt < nkt; kt += 4) {
    floatx4 acc = {0.f, 0.f, 0.f, 0.f};
    const short* kp = kb + (size_t)(kt * 16 + lm) * 1152 + quad * 8;
    const short* qp = qs + lm * 200 + quad * 8;
#pragma unroll
    for (int c6 = 0; c6 < 6; ++c6) {
      short8 af = *(const short8*)(qp + c6 * 32);
      short8 bf = *(const short8*)(kp + c6 * 32);
      acc = __builtin_amdgcn_mfma_f32_16x16x32_bf16(af, bf, acc, 0, 0, 0);
    }
#pragma unroll
    for (int r2 = 0; r2 < 4; ++r2)
      sc[(quad * 4 + r2) * SCW + kt * 16 + lm] = acc[r2] * 0.07216878364870323f;
  }
  __syncthreads();

  // softmax (store unnormalized exp, keep 1/l)
  {
    int row = tid >> 4, c0 = tid & 15;
    float* sp = sc + row * SCW;
    float mx = -1e30f;
    for (int k2 = c0; k2 < T; k2 += 16) mx = fmaxf(mx, sp[k2]);
#pragma unroll
    for (int off2 = 8; off2; off2 >>= 1) mx = fmaxf(mx, __shfl_down(mx, off2, 16));
    mx = __shfl(mx, 0, 16);
    float l = 0.f;
    for (int k2 = c0; k2 < T; k2 += 16) { float e = __expf(sp[k2] - mx); sp[k2] = e; l += e; }
#pragma unroll
    for (int off2 = 8; off2; off2 >>= 1) l += __shfl_down(l, off2, 16);
    if (c0 == 0) invl[row] = 1.f / l;
  }
  __syncthreads();

  // O[q][d] = P @ V via MFMA; wave owns d-tiles {wave, wave+4, wave+8}
  floatx4 oacc[3] = {};
  const int nkc = T >> 5;
  for (int kc = 0; kc < nkc; ++kc) {
    const float* pp = sc + lm * SCW + kc * 32 + quad * 8;
    float4 p0 = *(const float4*)pp;
    float4 p1 = *(const float4*)(pp + 4);
    short8 af;
    af[0] = f2b(p0.x); af[1] = f2b(p0.y); af[2] = f2b(p0.z); af[3] = f2b(p0.w);
    af[4] = f2b(p1.x); af[5] = f2b(p1.y); af[6] = f2b(p1.z); af[7] = f2b(p1.w);
#pragma unroll
    for (int dx = 0; dx < 3; ++dx) {
      int d = (wave + dx * 4) * 16 + lm;
      short8 bf = *(const short8*)(vb + (size_t)d * T + kc * 32 + quad * 8);
      oacc[dx] = __builtin_amdgcn_mfma_f32_16x16x32_bf16(af, bf, oacc[dx], 0, 0, 0);
    }
  }
#pragma unroll
  for (int dx = 0; dx < 3; ++dx) {
    int col = h * DH_ + (wave + dx * 4) * 16 + lm;
#pragma unroll
    for (int r2 = 0; r2 < 4; ++r2) {
      int qi = quad * 4 + r2;
      o[(size_t)(b * T + q0 + qi) * H_ + col] = f2b(oacc[dx][r2] * invl[qi]);
    }
  }
}

// ============ LayerNorm (H=384), wave per row; fp32 + optional bf16 out ============
__global__ __launch_bounds__(256) void ln_kernel(const float* __restrict__ X,
                                                 const float* __restrict__ sb,
                                                 float* __restrict__ Yf,
                                                 short* __restrict__ Yb, int M)
{
  int row  = blockIdx.x * 4 + (threadIdx.x >> 6);
  int lane = threadIdx.x & 63;
  const float* x = X + (size_t)row * H_;
  float v[6]; float s = 0.f, ss = 0.f;
#pragma unroll
  for (int i = 0; i < 6; ++i) { v[i] = x[lane + i * 64]; s += v[i]; ss += v[i] * v[i]; }
#pragma unroll
  for (int o = 32; o; o >>= 1) { s += __shfl_down(s, o, 64); ss += __shfl_down(ss, o, 64); }
  s = __shfl(s, 0, 64); ss = __shfl(ss, 0, 64);
  float mean = s * (1.0f / H_);
  float var  = ss * (1.0f / H_) - mean * mean;
  float r = rsqrtf(var + 1e-5f);
  float* yf = Yf + (size_t)row * H_;
#pragma unroll
  for (int i = 0; i < 6; ++i) {
    int c = lane + i * 64;
    float y = (v[i] - mean) * r * sb[c] + sb[H_ + c];
    yf[c] = y;
    if (Yb) Yb[(size_t)row * H_ + c] = f2b(y);
  }
}

// ============ length-pred GEMV ============
__global__ void gemv_kernel(const float* __restrict__ A, const float* __restrict__ w,
                            const float* __restrict__ bflt, float* __restrict__ out, int M)
{
  int row  = blockIdx.x * 4 + (threadIdx.x >> 6);
  int lane = threadIdx.x & 63;
  const float* a = A + (size_t)row * H_;
  float s = 0.f;
#pragma unroll
  for (int i = 0; i < 6; ++i) s += a[lane + i * 64] * w[lane + i * 64];
#pragma unroll
  for (int o = 32; o; o >>= 1) s += __shfl_down(s, o, 64);
  if (lane == 0) out[row] = s + bflt[0];
}

__global__ void cumsum_kernel(const int* __restrict__ al, int* __restrict__ cum) {
  int b = threadIdx.x;
  if (b < B_) {
    int acc = 0;
    for (int s = 0; s < S_; ++s) { acc += al[b * S_ + s]; cum[b * S_ + s] = acc; }
  }
}

// ============ length regulator + posenc ============
__global__ void expand_kernel(const float* __restrict__ xe, const int* __restrict__ cum,
                              float* __restrict__ yf, short* __restrict__ yb) {
  int t = blockIdx.x, b = blockIdx.y;
  const int* c = cum + b * S_;
  int lo = 0, hi = S_;
  while (lo < hi) { int mid = (lo + hi) >> 1; if (c[mid] <= t) lo = mid + 1; else hi = mid; }
  int idx = lo < S_ ? lo : S_ - 1;
  bool valid = t < c[S_ - 1];
  const float* src = xe + ((size_t)b * S_ + idx) * H_;
  float* df = yf + ((size_t)b * TOUT_ + t) * H_;
  short* db = yb + ((size_t)b * TOUT_ + t) * H_;
  for (int i = threadIdx.x; i < H_; i += blockDim.x) {
    float v = (valid ? src[i] : 0.f) + pe_val(t, i);
    df[i] = v; db[i] = f2b(v);
  }
}

// ================= host orchestration =================
static inline void gemm(const short* A, const short* Wt, const float* bias, const float* res,
                        float* Cf, short* Cb, int M, int N, int Kd, int T, int ntaps,
                        int Nout, int flags, hipStream_t st) {
  dim3 g(N / 128, M / 128);
  mfma_gemm<<<g, 256, 0, st>>>(A, Wt, bias, res, Cf, Cb, M, N, Kd, T, ntaps, Nout, flags);
}

struct LayerW { const short *attn, *c1, *c2; const float *ab, *c1b, *c2b, *ln; };

static void fft_block(float* x, short* xb, short* qkvb, short* ob, short* vtb, short* h2b,
                      const LayerW& w, int T, hipStream_t st)
{
  int M = B_ * T;
  const size_t msz = (size_t)H_ * H_;
  // fused QKV (N=1152) -> bf16
  gemm(xb, w.attn, w.ab, nullptr, nullptr, qkvb, M, 1152, H_, T, 1, 0, F_BIAS | F_STB, st);
  vtrans_kernel<<<dim3(T / 32, 12, B_), 256, 0, st>>>(qkvb, vtb, T);
  attn_mfma<<<dim3(T / 16, NH_, B_), 256, 0, st>>>(qkvb, vtb, ob, T);
  // O-proj + residual (in-place on x)
  gemm(ob, w.attn + 3 * msz, w.ab + 3 * H_, x, x, nullptr, M, H_, H_, T, 1, 0,
       F_BIAS | F_RES | F_STF, st);
  ln_kernel<<<M / 4, 256, 0, st>>>(x, w.ln, x, xb, M);
  // conv1 (3 taps) + ReLU -> bf16
  gemm(xb, w.c1, w.c1b, nullptr, nullptr, h2b, M, H2_, H_, T, 3, 0, F_BIAS | F_RELU | F_STB, st);
  // conv2 (3 taps) + residual (in-place on x)
  gemm(h2b, w.c2, w.c2b, x, x, nullptr, M, H_, H2_, T, 3, 0, F_BIAS | F_RES | F_STF, st);
  ln_kernel<<<M / 4, 256, 0, st>>>(x, w.ln + 2 * H_, x, xb, M);
}

extern "C" void kernel_launch(void* const* d_in, const int* in_sizes, int n_in,
                              void* d_out, int out_size, void* d_ws, size_t ws_size,
                              hipStream_t stream)
{
  (void)in_sizes; (void)n_in; (void)out_size; (void)ws_size;
  const int*   tokens      = (const int*)d_in[0];
  const int*   alignes     = (const int*)d_in[1];
  const float* tok_emb     = (const float*)d_in[2];
  const float* enc_attn_w  = (const float*)d_in[3];
  const float* enc_attn_b  = (const float*)d_in[4];
  const float* enc_conv1_w = (const float*)d_in[5];
  const float* enc_conv1_b = (const float*)d_in[6];
  const float* enc_conv2_w = (const float*)d_in[7];
  const float* enc_conv2_b = (const float*)d_in[8];
  const float* enc_ln      = (const float*)d_in[9];
  const float* dec_attn_w  = (const float*)d_in[10];
  const float* dec_attn_b  = (const float*)d_in[11];
  const float* dec_conv1_w = (const float*)d_in[12];
  const float* dec_conv1_b = (const float*)d_in[13];
  const float* dec_conv2_w = (const float*)d_in[14];
  const float* dec_conv2_b = (const float*)d_in[15];
  const float* dec_ln      = (const float*)d_in[16];
  const float* al_c1w      = (const float*)d_in[17];
  const float* al_c1b      = (const float*)d_in[18];
  const float* al_c2w      = (const float*)d_in[19];
  const float* al_c2b      = (const float*)d_in[20];
  const float* al_ln       = (const float*)d_in[21];
  const float* al_lin_w    = (const float*)d_in[22];
  const float* al_lin_b    = (const float*)d_in[23];
  const float* dec_lin_w   = (const float*)d_in[24];
  const float* dec_lin_b   = (const float*)d_in[25];

  // ---- workspace carve-up (256B aligned) ----
  char* base = (char*)d_ws;
  size_t off = 0;
  auto alloc = [&](size_t bytes) -> char* {
    char* p = base + off;
    off += (bytes + 255) & ~(size_t)255;
    return p;
  };
  const size_t ME = (size_t)B_ * S_;      // 4096
  const size_t MD = (size_t)B_ * TOUT_;   // 16384
  float* xe   = (float*)alloc(ME * H_ * 4);
  short* xeb  = (short*)alloc(ME * H_ * 2);
  float* xd   = (float*)alloc(MD * H_ * 4);
  short* xdb  = (short*)alloc(MD * H_ * 2);
  short* qkvb = (short*)alloc(MD * 1152 * 2);
  short* ob   = (short*)alloc(MD * H_ * 2);
  short* h2b  = (short*)alloc(MD * H2_ * 2);     // first 12.6MB doubles as vtb
  short* vtb  = h2b;
  short* wAt  = (short*)alloc((size_t)32 * H_ * H_ * 2);
  short* wAl  = (short*)alloc((size_t)6 * H_ * H_ * 2);
  short* wC1  = (short*)alloc((size_t)24 * H_ * H2_ * 2);
  short* wC2  = (short*)alloc((size_t)24 * H_ * H2_ * 2);
  short* wMel = (short*)alloc((size_t)128 * H_ * 2);
  int*   cum  = (int*)alloc(ME * 4);
  float* alf  = xd;                // aligner fp32 scratch (xd unused until expand)
  short* alb  = xdb;               // aligner bf16 scratch

  float* mel_out = (float*)d_out;
  float* len_out = mel_out + (size_t)B_ * MEL_ * TOUT_;

  // ---- weight prep (fp32 -> bf16, transposed [N][K]) ----
  wtrans_kernel<<<dim3(12, 12, 32), 256, 0, stream>>>(enc_attn_w, dec_attn_w, 16, H_, H_, wAt);
  wtrans_kernel<<<dim3(12, 12, 6),  256, 0, stream>>>(al_c1w, al_c2w, 3, H_, H_, wAl);
  wtrans_kernel<<<dim3(48, 12, 24), 256, 0, stream>>>(enc_conv1_w, dec_conv1_w, 12, H_, H2_, wC1);
  wtrans_kernel<<<dim3(12, 48, 24), 256, 0, stream>>>(enc_conv2_w, dec_conv2_w, 12, H2_, H_, wC2);
  melpad_kernel<<<dim3(128 * H_ / 256), 256, 0, stream>>>(dec_lin_w, wMel);

  // ---- encoder ----
  embed_kernel<<<dim3(B_ * S_), 128, 0, stream>>>(tokens, tok_emb, xe, xeb);
  for (int i = 0; i < L_; ++i) {
    LayerW w;
    w.attn = wAt + (size_t)i * 4 * H_ * H_;
    w.c1   = wC1 + (size_t)i * 3 * H_ * H2_;
    w.c2   = wC2 + (size_t)i * 3 * H_ * H2_;
    w.ab   = enc_attn_b + (size_t)i * 4 * H_;
    w.c1b  = enc_conv1_b + (size_t)i * H2_;
    w.c2b  = enc_conv2_b + (size_t)i * H_;
    w.ln   = enc_ln + (size_t)i * 4 * H_;
    fft_block(xe, xeb, qkvb, ob, vtb, h2b, w, S_, stream);
  }

  // ---- aligner (uses xeb; scratch aliases xd/xdb, free until expand) ----
  {
    int Ma = B_ * S_;
    gemm(xeb, wAl, al_c1b, nullptr, alf, nullptr, Ma, H_, H_, S_, 3, 0,
         F_BIAS | F_RELU | F_STF, stream);
    ln_kernel<<<Ma / 4, 256, 0, stream>>>(alf, al_ln, alf, alb, Ma);
    gemm(alb, wAl + (size_t)3 * H_ * H_, al_c2b, nullptr, alf, nullptr, Ma, H_, H_, S_, 3, 0,
         F_BIAS | F_RELU | F_STF, stream);
    ln_kernel<<<Ma / 4, 256, 0, stream>>>(alf, al_ln + 2 * H_, alf, (short*)nullptr, Ma);
    gemv_kernel<<<Ma / 4, 256, 0, stream>>>(alf, al_lin_w, al_lin_b, len_out, Ma);
  }

  // ---- length regulator + decoder posenc ----
  cumsum_kernel<<<1, 64, 0, stream>>>(alignes, cum);
  expand_kernel<<<dim3(TOUT_, B_), 128, 0, stream>>>(xe, cum, xd, xdb);

  // ---- decoder ----
  for (int i = 0; i < L_; ++i) {
    LayerW w;
    w.attn = wAt + (size_t)(16 + i * 4) * H_ * H_;
    w.c1   = wC1 + (size_t)(12 + i * 3) * H_ * H2_;
    w.c2   = wC2 + (size_t)(12 + i * 3) * H_ * H2_;
    w.ab   = dec_attn_b + (size_t)i * 4 * H_;
    w.c1b  = dec_conv1_b + (size_t)i * H2_;
    w.c2b  = dec_conv2_b + (size_t)i * H_;
    w.ln   = dec_ln + (size_t)i * 4 * H_;
    fft_block(xd, xdb, qkvb, ob, vtb, h2b, w, TOUT_, stream);
  }

  // ---- final mel projection, transposed write [B, MEL, TOUT] ----
  gemm(xdb, wMel, dec_lin_b, nullptr, mel_out, nullptr, B_ * TOUT_, 128, H_, TOUT_, 1,
       MEL_, F_BIAS | F_TRANS, stream);
}

// Round 3
// 3362.854 us; speedup vs baseline: 9.8134x; 1.2073x over previous
//
#include <hip/hip_runtime.h>
#include <cstdint>
#include <cstddef>

// ---- model constants ----
#define B_    16
#define S_    256
#define H_    384
#define H2_   1536
#define NH_   2
#define DH_   192
#define TOUT_ 1024
#define MEL_  80
#define L_    4

// ---- gemm epilogue flags ----
#define F_BIAS  1
#define F_RES   2
#define F_RELU  4
#define F_STF   8
#define F_STB   16
#define F_TRANS 32

typedef __attribute__((ext_vector_type(8))) short short8;
typedef __attribute__((ext_vector_type(4))) float floatx4;

typedef const __attribute__((address_space(1))) unsigned int* as1p;
typedef __attribute__((address_space(3))) unsigned int* as3p;

// async global->LDS, 16B per lane; LDS dest = wave-uniform base + lane*16
__device__ __forceinline__ void gld16(const void* g, void* l) {
  __builtin_amdgcn_global_load_lds((as1p)g, (as3p)l, 16, 0, 0);
}

// fp32 -> bf16 bits, round-to-nearest-even
__device__ __forceinline__ short f2b(float f) {
  union { float f; unsigned u; } v; v.f = f;
  unsigned r = (v.u + 0x7fffu + ((v.u >> 16) & 1u)) >> 16;
  return (short)r;
}

__device__ __forceinline__ float pe_val(int t, int i) {
  int j = i >> 1;
  float den = __expf(-9.210340371976184f * (float)(2 * j) / (float)H_);
  float ang = (float)t * den;
  return (i & 1) ? __cosf(ang) : __sinf(ang);
}

// ============ weight prep ============
__global__ __launch_bounds__(256) void wtrans_kernel(const float* __restrict__ sa,
                                                     const float* __restrict__ sb,
                                                     int na, int K, int N,
                                                     short* __restrict__ dst) {
  __shared__ float t[32][33];
  int id = blockIdx.z;
  const float* s = (id < na) ? sa + (size_t)id * K * N : sb + (size_t)(id - na) * K * N;
  short* o = dst + (size_t)id * K * N;
  int n0 = blockIdx.x * 32, k0 = blockIdx.y * 32;
  int tx = threadIdx.x & 31, ty = threadIdx.x >> 5;
#pragma unroll
  for (int i = 0; i < 4; ++i)
    t[ty + i * 8][tx] = s[(size_t)(k0 + ty + i * 8) * N + n0 + tx];
  __syncthreads();
#pragma unroll
  for (int i = 0; i < 4; ++i)
    o[(size_t)(n0 + ty + i * 8) * K + k0 + tx] = f2b(t[tx][ty + i * 8]);
}

__global__ void melpad_kernel(const float* __restrict__ w, short* __restrict__ dst) {
  int i = blockIdx.x * 256 + threadIdx.x;     // 128*384
  int n = i / H_, k = i - n * H_;
  dst[i] = (n < MEL_) ? f2b(w[(size_t)k * MEL_ + n]) : (short)0;
}

// ============ embedding + posenc ============
__global__ void embed_kernel(const int* __restrict__ tokens, const float* __restrict__ emb,
                             float* __restrict__ xf, short* __restrict__ xb) {
  int bs = blockIdx.x;
  int t  = bs & (S_ - 1);
  int tok = tokens[bs];
  const float* e = emb + (size_t)tok * H_;
  float* of = xf + (size_t)bs * H_;
  short* ob = xb + (size_t)bs * H_;
  for (int i = threadIdx.x; i < H_; i += blockDim.x) {
    float v = e[i] * 19.595917942265423f + pe_val(t, i);
    of[i] = v; ob[i] = f2b(v);
  }
}

// ============ bf16 MFMA GEMM (global_load_lds staging, halo A-tile for conv taps) ============
// C[M,N] = sum_tap shift(A)[M,K] @ W[tap][K,N]; Wt is [ntaps][N][K] bf16 (k-contig)
template<int NTAPS>
__global__ __launch_bounds__(256) void mfma_gemm(
    const short* __restrict__ A, const short* __restrict__ Wt,
    const float* __restrict__ bias, const float* __restrict__ res,
    float* __restrict__ Cf, short* __restrict__ Cb, const short* __restrict__ zbuf,
    int M, int N, int Kd, int T, int Nout, int flags)
{
  constexpr int HB   = NTAPS / 2;
  constexpr int RA   = 128 + NTAPS - 1;          // A rows staged (halo)
  constexpr int RNDA = (RA + 63) / 64;           // 4KB staging rounds for A
  __shared__ __align__(16) short As[RA * 32];            // row-major, unpadded (gld16 layout)
  __shared__ __align__(16) short Bs[NTAPS * 128 * 32];
  const int tid = threadIdx.x;
  const int wave = tid >> 6, lane = tid & 63, quad = lane >> 4, lm = lane & 15;
  const int bm = blockIdx.y * 128, bn = blockIdx.x * 128;
  const int wm = (wave >> 1) * 64, wn = (wave & 1) * 64;
  const int b0 = bm / T, t0 = bm - b0 * T;       // 128 | T, block never crosses batch
  floatx4 acc[4][4] = {};

  for (int k0 = 0; k0 < Kd; k0 += 32) {
    // stage A rows [t0-HB, t0-HB+RA) — rounds of 64 rows (last round overlaps, same data)
#pragma unroll
    for (int j = 0; j < RNDA; ++j) {
      int r0 = (j == RNDA - 1) ? (RA - 64) : j * 64;
      int r = r0 + (tid >> 2);
      int t = t0 - HB + r;
      const short* g = (t >= 0 && t < T)
          ? (A + (size_t)(b0 * T + t) * Kd + k0 + (tid & 3) * 8) : zbuf;
      gld16(g, As + r0 * 32 + wave * 512);
    }
    // stage B: ntaps x 128 rows x 32, fully contiguous in LDS
#pragma unroll
    for (int j = 0; j < 2 * NTAPS; ++j) {
      int gi = j * 256 + tid;
      int tap = gi >> 9, rr = (gi >> 2) & 127, ch = gi & 3;
      const short* g = Wt + ((size_t)tap * N + bn + rr) * Kd + k0 + ch * 8;
      gld16(g, Bs + j * 2048 + wave * 512);
    }
    __syncthreads();
#pragma unroll
    for (int tap = 0; tap < NTAPS; ++tap) {
      short8 af[4], bfr[4];
#pragma unroll
      for (int mt = 0; mt < 4; ++mt)
        af[mt] = *(const short8*)(&As[(wm + mt * 16 + lm + tap) * 32 + quad * 8]);
#pragma unroll
      for (int nt = 0; nt < 4; ++nt)
        bfr[nt] = *(const short8*)(&Bs[tap * 4096 + (wn + nt * 16 + lm) * 32 + quad * 8]);
#pragma unroll
      for (int mt = 0; mt < 4; ++mt)
#pragma unroll
        for (int nt = 0; nt < 4; ++nt)
          acc[mt][nt] = __builtin_amdgcn_mfma_f32_16x16x32_bf16(af[mt], bfr[nt],
                                                                acc[mt][nt], 0, 0, 0);
    }
    __syncthreads();
  }

#pragma unroll
  for (int mt = 0; mt < 4; ++mt) {
#pragma unroll
    for (int r2 = 0; r2 < 4; ++r2) {
      int gm = bm + wm + mt * 16 + quad * 4 + r2;
#pragma unroll
      for (int nt = 0; nt < 4; ++nt) {
        int gn = bn + wn + nt * 16 + lm;
        float v = acc[mt][nt][r2];
        if (flags & F_TRANS) {
          if (gn < Nout) {
            if (flags & F_BIAS) v += bias[gn];
            int bb = gm / T, tt = gm - bb * T;
            Cf[((size_t)bb * Nout + gn) * T + tt] = v;
          }
          continue;
        }
        if (flags & F_BIAS) v += bias[gn];
        size_t idx = (size_t)gm * N + gn;
        if (flags & F_RES) v += res[idx];
        if (flags & F_RELU) v = fmaxf(v, 0.f);
        if (flags & F_STF) Cf[idx] = v;
        if (flags & F_STB) Cb[idx] = f2b(v);
      }
    }
  }
}

// ============ V transpose: QKV cols 768..1151 -> Vt[b][h][d][T] ============
__global__ __launch_bounds__(256) void vtrans_kernel(const short* __restrict__ qkv,
                                                     short* __restrict__ vt, int T) {
  __shared__ short tile[32][34];
  int b = blockIdx.z, d0 = blockIdx.y * 32, t0 = blockIdx.x * 32;
  int tx = threadIdx.x & 31, ty = threadIdx.x >> 5;
#pragma unroll
  for (int i = 0; i < 4; ++i)
    tile[ty + i * 8][tx] = qkv[(size_t)(b * T + t0 + ty + i * 8) * 1152 + 768 + d0 + tx];
  __syncthreads();
  int h = (d0 >= DH_) ? 1 : 0;
  int dd0 = d0 - h * DH_;
#pragma unroll
  for (int i = 0; i < 4; ++i)
    vt[((size_t)((b * NH_ + h) * DH_) + dd0 + ty + i * 8) * T + t0 + tx] = tile[tx][ty + i * 8];
}

// ============ MFMA attention v2: scores in registers, bf16 P in LDS ============
template<int T>
__global__ __launch_bounds__(256) void attn_mfma(const short* __restrict__ qkv,
                                                 const short* __restrict__ vt,
                                                 short* __restrict__ o)
{
  constexpr int PK = T / 64;          // k-tiles per wave
  constexpr int PW = T + 8;           // P row width (shorts)
  __shared__ __align__(16) short qs[16 * 200];
  __shared__ __align__(16) short P[16 * PW];
  __shared__ float red[4][16];
  const int tid = threadIdx.x;
  const int wave = tid >> 6, lane = tid & 63, quad = lane >> 4, lm = lane & 15;
  const int q0 = blockIdx.x * 16, h = blockIdx.y, b = blockIdx.z;
  const short* qb = qkv + (size_t)b * T * 1152 + h * DH_;
  const short* kb = qb + 384;
  const short* vb = vt + (size_t)(b * NH_ + h) * DH_ * T;

  for (int u = tid; u < 16 * 24; u += 256) {
    int r = u / 24, c = u - r * 24;
    *(int4*)(qs + r * 200 + c * 8) = *(const int4*)(qb + (size_t)(q0 + r) * 1152 + c * 8);
  }
  __syncthreads();

  short8 qf[6];
#pragma unroll
  for (int c6 = 0; c6 < 6; ++c6)
    qf[c6] = *(const short8*)(qs + lm * 200 + c6 * 32 + quad * 8);

  // scores in registers: sacc[i][r2] = S[q=quad*4+r2][k=(i*4+wave)*16+lm]
  floatx4 sacc[PK];
#pragma unroll
  for (int i = 0; i < PK; ++i) {
    int kt = i * 4 + wave;
    floatx4 a = {0.f, 0.f, 0.f, 0.f};
    const short* kp = kb + (size_t)(kt * 16 + lm) * 1152 + quad * 8;
#pragma unroll
    for (int c6 = 0; c6 < 6; ++c6)
      a = __builtin_amdgcn_mfma_f32_16x16x32_bf16(qf[c6], *(const short8*)(kp + c6 * 32),
                                                  a, 0, 0, 0);
#pragma unroll
    for (int r2 = 0; r2 < 4; ++r2) a[r2] *= 0.07216878364870323f;
    sacc[i] = a;
  }

  // row max: in-lane over i, shuffle over lm, LDS over waves
  float mx[4];
#pragma unroll
  for (int r2 = 0; r2 < 4; ++r2) {
    float m = sacc[0][r2];
#pragma unroll
    for (int i = 1; i < PK; ++i) m = fmaxf(m, sacc[i][r2]);
#pragma unroll
    for (int off = 1; off < 16; off <<= 1) m = fmaxf(m, __shfl_xor(m, off, 64));
    mx[r2] = m;
  }
  if (lm == 0) {
#pragma unroll
    for (int r2 = 0; r2 < 4; ++r2) red[wave][quad * 4 + r2] = mx[r2];
  }
  __syncthreads();
  float gm[4];
#pragma unroll
  for (int r2 = 0; r2 < 4; ++r2) {
    int row = quad * 4 + r2;
    gm[r2] = fmaxf(fmaxf(red[0][row], red[1][row]), fmaxf(red[2][row], red[3][row]));
  }
  __syncthreads();

  // exp (unnormalized) -> bf16 P in LDS; row sums
  float sm[4] = {0.f, 0.f, 0.f, 0.f};
#pragma unroll
  for (int i = 0; i < PK; ++i) {
#pragma unroll
    for (int r2 = 0; r2 < 4; ++r2) {
      float e = __expf(sacc[i][r2] - gm[r2]);
      sm[r2] += e;
      P[(quad * 4 + r2) * PW + (i * 4 + wave) * 16 + lm] = f2b(e);
    }
  }
#pragma unroll
  for (int r2 = 0; r2 < 4; ++r2) {
#pragma unroll
    for (int off = 1; off < 16; off <<= 1) sm[r2] += __shfl_xor(sm[r2], off, 64);
  }
  if (lm == 0) {
#pragma unroll
    for (int r2 = 0; r2 < 4; ++r2) red[wave][quad * 4 + r2] = sm[r2];
  }
  __syncthreads();
  float il[4];
#pragma unroll
  for (int r2 = 0; r2 < 4; ++r2) {
    int row = quad * 4 + r2;
    il[r2] = 1.f / (red[0][row] + red[1][row] + red[2][row] + red[3][row]);
  }

  // O = P @ V^T via MFMA; wave owns d-tiles {wave, wave+4, wave+8}
  floatx4 oacc[3] = {};
  for (int kc = 0; kc < T / 32; ++kc) {
    short8 af = *(const short8*)(P + lm * PW + kc * 32 + quad * 8);
#pragma unroll
    for (int dx = 0; dx < 3; ++dx) {
      short8 bf = *(const short8*)(vb + (size_t)((wave + dx * 4) * 16 + lm) * T + kc * 32 + quad * 8);
      oacc[dx] = __builtin_amdgcn_mfma_f32_16x16x32_bf16(af, bf, oacc[dx], 0, 0, 0);
    }
  }
#pragma unroll
  for (int dx = 0; dx < 3; ++dx) {
    int col = h * DH_ + (wave + dx * 4) * 16 + lm;
#pragma unroll
    for (int r2 = 0; r2 < 4; ++r2)
      o[(size_t)(b * T + q0 + quad * 4 + r2) * H_ + col] = f2b(oacc[dx][r2] * il[r2]);
  }
}

// ============ LayerNorm (H=384), wave per row ============
__global__ __launch_bounds__(256) void ln_kernel(const float* __restrict__ X,
                                                 const float* __restrict__ sb,
                                                 float* __restrict__ Yf,
                                                 short* __restrict__ Yb, int M)
{
  int row  = blockIdx.x * 4 + (threadIdx.x >> 6);
  int lane = threadIdx.x & 63;
  const float* x = X + (size_t)row * H_;
  float v[6]; float s = 0.f, ss = 0.f;
#pragma unroll
  for (int i = 0; i < 6; ++i) { v[i] = x[lane + i * 64]; s += v[i]; ss += v[i] * v[i]; }
#pragma unroll
  for (int o = 32; o; o >>= 1) { s += __shfl_down(s, o, 64); ss += __shfl_down(ss, o, 64); }
  s = __shfl(s, 0, 64); ss = __shfl(ss, 0, 64);
  float mean = s * (1.0f / H_);
  float var  = ss * (1.0f / H_) - mean * mean;
  float r = rsqrtf(var + 1e-5f);
  float* yf = Yf + (size_t)row * H_;
#pragma unroll
  for (int i = 0; i < 6; ++i) {
    int c = lane + i * 64;
    float y = (v[i] - mean) * r * sb[c] + sb[H_ + c];
    yf[c] = y;
    if (Yb) Yb[(size_t)row * H_ + c] = f2b(y);
  }
}

// ============ length-pred GEMV ============
__global__ void gemv_kernel(const float* __restrict__ A, const float* __restrict__ w,
                            const float* __restrict__ bflt, float* __restrict__ out, int M)
{
  int row  = blockIdx.x * 4 + (threadIdx.x >> 6);
  int lane = threadIdx.x & 63;
  const float* a = A + (size_t)row * H_;
  float s = 0.f;
#pragma unroll
  for (int i = 0; i < 6; ++i) s += a[lane + i * 64] * w[lane + i * 64];
#pragma unroll
  for (int o = 32; o; o >>= 1) s += __shfl_down(s, o, 64);
  if (lane == 0) out[row] = s + bflt[0];
}

__global__ void cumsum_kernel(const int* __restrict__ al, int* __restrict__ cum) {
  int b = threadIdx.x;
  if (b < B_) {
    int acc = 0;
    for (int s = 0; s < S_; ++s) { acc += al[b * S_ + s]; cum[b * S_ + s] = acc; }
  }
}

__global__ void expand_kernel(const float* __restrict__ xe, const int* __restrict__ cum,
                              float* __restrict__ yf, short* __restrict__ yb) {
  int t = blockIdx.x, b = blockIdx.y;
  const int* c = cum + b * S_;
  int lo = 0, hi = S_;
  while (lo < hi) { int mid = (lo + hi) >> 1; if (c[mid] <= t) lo = mid + 1; else hi = mid; }
  int idx = lo < S_ ? lo : S_ - 1;
  bool valid = t < c[S_ - 1];
  const float* src = xe + ((size_t)b * S_ + idx) * H_;
  float* df = yf + ((size_t)b * TOUT_ + t) * H_;
  short* db = yb + ((size_t)b * TOUT_ + t) * H_;
  for (int i = threadIdx.x; i < H_; i += blockDim.x) {
    float v = (valid ? src[i] : 0.f) + pe_val(t, i);
    df[i] = v; db[i] = f2b(v);
  }
}

// ================= host orchestration =================
static inline void gemm(const short* A, const short* Wt, const float* bias, const float* res,
                        float* Cf, short* Cb, const short* zbuf, int M, int N, int Kd, int T,
                        int ntaps, int Nout, int flags, hipStream_t st) {
  dim3 g(N / 128, M / 128);
  if (ntaps == 3)
    mfma_gemm<3><<<g, 256, 0, st>>>(A, Wt, bias, res, Cf, Cb, zbuf, M, N, Kd, T, Nout, flags);
  else
    mfma_gemm<1><<<g, 256, 0, st>>>(A, Wt, bias, res, Cf, Cb, zbuf, M, N, Kd, T, Nout, flags);
}

struct LayerW { const short *attn, *c1, *c2; const float *ab, *c1b, *c2b, *ln; };

static void fft_block(float* x, short* xb, short* qkvb, short* ob, short* vtb, short* h2b,
                      const short* zbuf, const LayerW& w, int T, hipStream_t st)
{
  int M = B_ * T;
  const size_t msz = (size_t)H_ * H_;
  gemm(xb, w.attn, w.ab, nullptr, nullptr, qkvb, zbuf, M, 1152, H_, T, 1, 0, F_BIAS | F_STB, st);
  vtrans_kernel<<<dim3(T / 32, 12, B_), 256, 0, st>>>(qkvb, vtb, T);
  if (T == 256) attn_mfma<256><<<dim3(T / 16, NH_, B_), 256, 0, st>>>(qkvb, vtb, ob);
  else          attn_mfma<1024><<<dim3(T / 16, NH_, B_), 256, 0, st>>>(qkvb, vtb, ob);
  gemm(ob, w.attn + 3 * msz, w.ab + 3 * H_, x, x, nullptr, zbuf, M, H_, H_, T, 1, 0,
       F_BIAS | F_RES | F_STF, st);
  ln_kernel<<<M / 4, 256, 0, st>>>(x, w.ln, x, xb, M);
  gemm(xb, w.c1, w.c1b, nullptr, nullptr, h2b, zbuf, M, H2_, H_, T, 3, 0,
       F_BIAS | F_RELU | F_STB, st);
  gemm(h2b, w.c2, w.c2b, x, x, nullptr, zbuf, M, H_, H2_, T, 3, 0, F_BIAS | F_RES | F_STF, st);
  ln_kernel<<<M / 4, 256, 0, st>>>(x, w.ln + 2 * H_, x, xb, M);
}

extern "C" void kernel_launch(void* const* d_in, const int* in_sizes, int n_in,
                              void* d_out, int out_size, void* d_ws, size_t ws_size,
                              hipStream_t stream)
{
  (void)in_sizes; (void)n_in; (void)out_size; (void)ws_size;
  const int*   tokens      = (const int*)d_in[0];
  const int*   alignes     = (const int*)d_in[1];
  const float* tok_emb     = (const float*)d_in[2];
  const float* enc_attn_w  = (const float*)d_in[3];
  const float* enc_attn_b  = (const float*)d_in[4];
  const float* enc_conv1_w = (const float*)d_in[5];
  const float* enc_conv1_b = (const float*)d_in[6];
  const float* enc_conv2_w = (const float*)d_in[7];
  const float* enc_conv2_b = (const float*)d_in[8];
  const float* enc_ln      = (const float*)d_in[9];
  const float* dec_attn_w  = (const float*)d_in[10];
  const float* dec_attn_b  = (const float*)d_in[11];
  const float* dec_conv1_w = (const float*)d_in[12];
  const float* dec_conv1_b = (const float*)d_in[13];
  const float* dec_conv2_w = (const float*)d_in[14];
  const float* dec_conv2_b = (const float*)d_in[15];
  const float* dec_ln      = (const float*)d_in[16];
  const float* al_c1w      = (const float*)d_in[17];
  const float* al_c1b      = (const float*)d_in[18];
  const float* al_c2w      = (const float*)d_in[19];
  const float* al_c2b      = (const float*)d_in[20];
  const float* al_ln       = (const float*)d_in[21];
  const float* al_lin_w    = (const float*)d_in[22];
  const float* al_lin_b    = (const float*)d_in[23];
  const float* dec_lin_w   = (const float*)d_in[24];
  const float* dec_lin_b   = (const float*)d_in[25];

  char* base = (char*)d_ws;
  size_t off = 0;
  auto alloc = [&](size_t bytes) -> char* {
    char* p = base + off;
    off += (bytes + 255) & ~(size_t)255;
    return p;
  };
  const size_t ME = (size_t)B_ * S_;      // 4096
  const size_t MD = (size_t)B_ * TOUT_;   // 16384
  float* xe   = (float*)alloc(ME * H_ * 4);
  short* xeb  = (short*)alloc(ME * H_ * 2);
  float* xd   = (float*)alloc(MD * H_ * 4);
  short* xdb  = (short*)alloc(MD * H_ * 2);
  short* qkvb = (short*)alloc(MD * 1152 * 2);
  short* ob   = (short*)alloc(MD * H_ * 2);
  short* h2b  = (short*)alloc(MD * H2_ * 2);     // first 12.6MB doubles as vtb
  short* vtb  = h2b;
  short* wAt  = (short*)alloc((size_t)32 * H_ * H_ * 2);
  short* wAl  = (short*)alloc((size_t)6 * H_ * H_ * 2);
  short* wC1  = (short*)alloc((size_t)24 * H_ * H2_ * 2);
  short* wC2  = (short*)alloc((size_t)24 * H_ * H2_ * 2);
  short* wMel = (short*)alloc((size_t)128 * H_ * 2);
  int*   cum  = (int*)alloc(ME * 4);
  short* zbuf = (short*)alloc(256);
  float* alf  = xd;                // aligner scratch (xd/xdb free until expand)
  short* alb  = xdb;

  float* mel_out = (float*)d_out;
  float* len_out = mel_out + (size_t)B_ * MEL_ * TOUT_;

  hipMemsetAsync(zbuf, 0, 256, stream);

  // ---- weight prep ----
  wtrans_kernel<<<dim3(12, 12, 32), 256, 0, stream>>>(enc_attn_w, dec_attn_w, 16, H_, H_, wAt);
  wtrans_kernel<<<dim3(12, 12, 6),  256, 0, stream>>>(al_c1w, al_c2w, 3, H_, H_, wAl);
  wtrans_kernel<<<dim3(48, 12, 24), 256, 0, stream>>>(enc_conv1_w, dec_conv1_w, 12, H_, H2_, wC1);
  wtrans_kernel<<<dim3(12, 48, 24), 256, 0, stream>>>(enc_conv2_w, dec_conv2_w, 12, H2_, H_, wC2);
  melpad_kernel<<<dim3(128 * H_ / 256), 256, 0, stream>>>(dec_lin_w, wMel);

  // ---- encoder ----
  embed_kernel<<<dim3(B_ * S_), 128, 0, stream>>>(tokens, tok_emb, xe, xeb);
  for (int i = 0; i < L_; ++i) {
    LayerW w;
    w.attn = wAt + (size_t)i * 4 * H_ * H_;
    w.c1   = wC1 + (size_t)i * 3 * H_ * H2_;
    w.c2   = wC2 + (size_t)i * 3 * H_ * H2_;
    w.ab   = enc_attn_b + (size_t)i * 4 * H_;
    w.c1b  = enc_conv1_b + (size_t)i * H2_;
    w.c2b  = enc_conv2_b + (size_t)i * H_;
    w.ln   = enc_ln + (size_t)i * 4 * H_;
    fft_block(xe, xeb, qkvb, ob, vtb, h2b, zbuf, w, S_, stream);
  }

  // ---- aligner ----
  {
    int Ma = B_ * S_;
    gemm(xeb, wAl, al_c1b, nullptr, alf, nullptr, zbuf, Ma, H_, H_, S_, 3, 0,
         F_BIAS | F_RELU | F_STF, stream);
    ln_kernel<<<Ma / 4, 256, 0, stream>>>(alf, al_ln, alf, alb, Ma);
    gemm(alb, wAl + (size_t)3 * H_ * H_, al_c2b, nullptr, alf, nullptr, zbuf, Ma, H_, H_, S_,
         3, 0, F_BIAS | F_RELU | F_STF, stream);
    ln_kernel<<<Ma / 4, 256, 0, stream>>>(alf, al_ln + 2 * H_, alf, (short*)nullptr, Ma);
    gemv_kernel<<<Ma / 4, 256, 0, stream>>>(alf, al_lin_w, al_lin_b, len_out, Ma);
  }

  // ---- length regulator ----
  cumsum_kernel<<<1, 64, 0, stream>>>(alignes, cum);
  expand_kernel<<<dim3(TOUT_, B_), 128, 0, stream>>>(xe, cum, xd, xdb);

  // ---- decoder ----
  for (int i = 0; i < L_; ++i) {
    LayerW w;
    w.attn = wAt + (size_t)(16 + i * 4) * H_ * H_;
    w.c1   = wC1 + (size_t)(12 + i * 3) * H_ * H2_;
    w.c2   = wC2 + (size_t)(12 + i * 3) * H_ * H2_;
    w.ab   = dec_attn_b + (size_t)i * 4 * H_;
    w.c1b  = dec_conv1_b + (size_t)i * H2_;
    w.c2b  = dec_conv2_b + (size_t)i * H_;
    w.ln   = dec_ln + (size_t)i * 4 * H_;
    fft_block(xd, xdb, qkvb, ob, vtb, h2b, zbuf, w, TOUT_, stream);
  }

  // ---- final mel projection, transposed write [B, MEL, TOUT] ----
  gemm(xdb, wMel, dec_lin_b, nullptr, mel_out, nullptr, zbuf, B_ * TOUT_, 128, H_, TOUT_,
       1, MEL_, F_BIAS | F_TRANS, stream);
}

// Round 4
// 2978.022 us; speedup vs baseline: 11.0816x; 1.1292x over previous
//
#include <hip/hip_runtime.h>
#include <cstdint>
#include <cstddef>

// ---- model constants ----
#define B_    16
#define S_    256
#define H_    384
#define H2_   1536
#define NH_   2
#define DH_   192
#define TOUT_ 1024
#define MEL_  80
#define L_    4

// ---- gemm epilogue flags ----
#define F_BIAS  1
#define F_RES   2
#define F_RELU  4
#define F_STF   8
#define F_STB   16
#define F_TRANS 32

typedef __attribute__((ext_vector_type(8))) short short8;
typedef __attribute__((ext_vector_type(4))) float floatx4;

typedef const __attribute__((address_space(1))) unsigned int* as1p;
typedef __attribute__((address_space(3))) unsigned int* as3p;

// async global->LDS, 16B per lane; LDS dest = wave-uniform base + lane*16
__device__ __forceinline__ void gld16(const void* g, void* l) {
  __builtin_amdgcn_global_load_lds((as1p)g, (as3p)l, 16, 0, 0);
}

// fp32 -> bf16 bits, round-to-nearest-even
__device__ __forceinline__ short f2b(float f) {
  union { float f; unsigned u; } v; v.f = f;
  unsigned r = (v.u + 0x7fffu + ((v.u >> 16) & 1u)) >> 16;
  return (short)r;
}

__device__ __forceinline__ float pe_val(int t, int i) {
  int j = i >> 1;
  float den = __expf(-9.210340371976184f * (float)(2 * j) / (float)H_);
  float ang = (float)t * den;
  return (i & 1) ? __cosf(ang) : __sinf(ang);
}

// ============ weight prep ============
__global__ __launch_bounds__(256) void wtrans_kernel(const float* __restrict__ sa,
                                                     const float* __restrict__ sb,
                                                     int na, int K, int N,
                                                     short* __restrict__ dst) {
  __shared__ float t[32][33];
  int id = blockIdx.z;
  const float* s = (id < na) ? sa + (size_t)id * K * N : sb + (size_t)(id - na) * K * N;
  short* o = dst + (size_t)id * K * N;
  int n0 = blockIdx.x * 32, k0 = blockIdx.y * 32;
  int tx = threadIdx.x & 31, ty = threadIdx.x >> 5;
#pragma unroll
  for (int i = 0; i < 4; ++i)
    t[ty + i * 8][tx] = s[(size_t)(k0 + ty + i * 8) * N + n0 + tx];
  __syncthreads();
#pragma unroll
  for (int i = 0; i < 4; ++i)
    o[(size_t)(n0 + ty + i * 8) * K + k0 + tx] = f2b(t[tx][ty + i * 8]);
}

__global__ void melpad_kernel(const float* __restrict__ w, short* __restrict__ dst) {
  int i = blockIdx.x * 256 + threadIdx.x;     // 128*384
  int n = i / H_, k = i - n * H_;
  dst[i] = (n < MEL_) ? f2b(w[(size_t)k * MEL_ + n]) : (short)0;
}

// ============ embedding + posenc ============
__global__ void embed_kernel(const int* __restrict__ tokens, const float* __restrict__ emb,
                             float* __restrict__ xf, short* __restrict__ xb) {
  int bs = blockIdx.x;
  int t  = bs & (S_ - 1);
  int tok = tokens[bs];
  const float* e = emb + (size_t)tok * H_;
  float* of = xf + (size_t)bs * H_;
  short* ob = xb + (size_t)bs * H_;
  for (int i = threadIdx.x; i < H_; i += blockDim.x) {
    float v = e[i] * 19.595917942265423f + pe_val(t, i);
    of[i] = v; ob[i] = f2b(v);
  }
}

// ============ bf16 MFMA GEMM (global_load_lds staging, halo A-tile for conv taps) ============
template<int NTAPS>
__global__ __launch_bounds__(256) void mfma_gemm(
    const short* __restrict__ A, const short* __restrict__ Wt,
    const float* __restrict__ bias, const float* __restrict__ res,
    float* __restrict__ Cf, short* __restrict__ Cb, const short* __restrict__ zbuf,
    int M, int N, int Kd, int T, int Nout, int flags)
{
  constexpr int HB   = NTAPS / 2;
  constexpr int RA   = 128 + NTAPS - 1;
  constexpr int RNDA = (RA + 63) / 64;
  __shared__ __align__(16) short As[RA * 32];
  __shared__ __align__(16) short Bs[NTAPS * 128 * 32];
  const int tid = threadIdx.x;
  const int wave = tid >> 6, lane = tid & 63, quad = lane >> 4, lm = lane & 15;
  const int bm = blockIdx.y * 128, bn = blockIdx.x * 128;
  const int wm = (wave >> 1) * 64, wn = (wave & 1) * 64;
  const int b0 = bm / T, t0 = bm - b0 * T;
  floatx4 acc[4][4] = {};

  for (int k0 = 0; k0 < Kd; k0 += 32) {
#pragma unroll
    for (int j = 0; j < RNDA; ++j) {
      int r0 = (j == RNDA - 1) ? (RA - 64) : j * 64;
      int r = r0 + (tid >> 2);
      int t = t0 - HB + r;
      const short* g = (t >= 0 && t < T)
          ? (A + (size_t)(b0 * T + t) * Kd + k0 + (tid & 3) * 8) : zbuf;
      gld16(g, As + r0 * 32 + wave * 512);
    }
#pragma unroll
    for (int j = 0; j < 2 * NTAPS; ++j) {
      int gi = j * 256 + tid;
      int tap = gi >> 9, rr = (gi >> 2) & 127, ch = gi & 3;
      const short* g = Wt + ((size_t)tap * N + bn + rr) * Kd + k0 + ch * 8;
      gld16(g, Bs + j * 2048 + wave * 512);
    }
    __syncthreads();
#pragma unroll
    for (int tap = 0; tap < NTAPS; ++tap) {
      short8 af[4], bfr[4];
#pragma unroll
      for (int mt = 0; mt < 4; ++mt)
        af[mt] = *(const short8*)(&As[(wm + mt * 16 + lm + tap) * 32 + quad * 8]);
#pragma unroll
      for (int nt = 0; nt < 4; ++nt)
        bfr[nt] = *(const short8*)(&Bs[tap * 4096 + (wn + nt * 16 + lm) * 32 + quad * 8]);
#pragma unroll
      for (int mt = 0; mt < 4; ++mt)
#pragma unroll
        for (int nt = 0; nt < 4; ++nt)
          acc[mt][nt] = __builtin_amdgcn_mfma_f32_16x16x32_bf16(af[mt], bfr[nt],
                                                                acc[mt][nt], 0, 0, 0);
    }
    __syncthreads();
  }

#pragma unroll
  for (int mt = 0; mt < 4; ++mt) {
#pragma unroll
    for (int r2 = 0; r2 < 4; ++r2) {
      int gm = bm + wm + mt * 16 + quad * 4 + r2;
#pragma unroll
      for (int nt = 0; nt < 4; ++nt) {
        int gn = bn + wn + nt * 16 + lm;
        float v = acc[mt][nt][r2];
        if (flags & F_TRANS) {
          if (gn < Nout) {
            if (flags & F_BIAS) v += bias[gn];
            int bb = gm / T, tt = gm - bb * T;
            Cf[((size_t)bb * Nout + gn) * T + tt] = v;
          }
          continue;
        }
        if (flags & F_BIAS) v += bias[gn];
        size_t idx = (size_t)gm * N + gn;
        if (flags & F_RES) v += res[idx];
        if (flags & F_RELU) v = fmaxf(v, 0.f);
        if (flags & F_STF) Cf[idx] = v;
        if (flags & F_STB) Cb[idx] = f2b(v);
      }
    }
  }
}

// ============ V transpose: QKV cols 768..1151 -> Vt[b][h][d][T] ============
__global__ __launch_bounds__(256) void vtrans_kernel(const short* __restrict__ qkv,
                                                     short* __restrict__ vt, int T) {
  __shared__ short tile[32][34];
  int b = blockIdx.z, d0 = blockIdx.y * 32, t0 = blockIdx.x * 32;
  int tx = threadIdx.x & 31, ty = threadIdx.x >> 5;
#pragma unroll
  for (int i = 0; i < 4; ++i)
    tile[ty + i * 8][tx] = qkv[(size_t)(b * T + t0 + ty + i * 8) * 1152 + 768 + d0 + tx];
  __syncthreads();
  int h = (d0 >= DH_) ? 1 : 0;
  int dd0 = d0 - h * DH_;
#pragma unroll
  for (int i = 0; i < 4; ++i)
    vt[((size_t)((b * NH_ + h) * DH_) + dd0 + ty + i * 8) * T + t0 + tx] = tile[tx][ty + i * 8];
}

// ============ flash MFMA attention: block = (b, h, 64-query tile) ============
// K/V staged frag-major in LDS via global_load_lds, double-buffered; online softmax
// in registers; P transposed C->A layout through small per-wave LDS buffer.
// 1-D grid id = q*32 + (b*2+h): same (b,h) => same XCD (id%8) => K/V stays in one L2.
template<int T>
__global__ __launch_bounds__(256) void attn_flash(const short* __restrict__ qkv,
                                                  const short* __restrict__ vt,
                                                  short* __restrict__ o)
{
  constexpr int NKT = T / 32;
  __shared__ __align__(16) short Kb[2][6144];    // 32 keys x 192 d, frag-major
  __shared__ __align__(16) short Vb[2][6144];    // 192 d x 32 t, frag-major
  __shared__ __align__(16) short Pb[4][16 * 40]; // per-wave P, rows padded to 40
  const int tid = threadIdx.x;
  const int wave = tid >> 6, lane = tid & 63, quad = lane >> 4, lm = lane & 15;
  const int id = blockIdx.x;
  const int bh = id & 31, h = bh & 1, b = bh >> 1;
  const int q0 = (id >> 5) * 64;
  const short* qb = qkv + (size_t)b * T * 1152 + h * DH_;
  const short* kb = qb + 384;
  const short* vb = vt + (size_t)(b * NH_ + h) * DH_ * T;

  // Q A-fragments direct from global (one-time)
  short8 qf[6];
  {
    const short* qrow = qb + (size_t)(q0 + wave * 16 + lm) * 1152 + quad * 8;
#pragma unroll
    for (int c6 = 0; c6 < 6; ++c6) qf[c6] = *(const short8*)(qrow + c6 * 32);
  }

  auto stage = [&](int kc, int bi) {
#pragma unroll
    for (int j = 0; j < 3; ++j) {
      int g = j * 256 + tid;
      int lmg = g & 15, qg = (g >> 4) & 3, ct = g >> 6;   // ct in [0,12)
      int c6 = ct % 6, kt = ct / 6;
      gld16(kb + (size_t)(kc * 32 + kt * 16 + lmg) * 1152 + c6 * 32 + qg * 8,
            &Kb[bi][j * 2048 + wave * 512]);
    }
#pragma unroll
    for (int j = 0; j < 3; ++j) {
      int g = j * 256 + tid;
      int lmg = g & 15, qg = (g >> 4) & 3, dt = g >> 6;   // dt in [0,12)
      gld16(vb + (size_t)(dt * 16 + lmg) * T + kc * 32 + qg * 8,
            &Vb[bi][j * 2048 + wave * 512]);
    }
  };

  float m_r[4] = {-1e30f, -1e30f, -1e30f, -1e30f};
  float l_r[4] = {0.f, 0.f, 0.f, 0.f};
  floatx4 oacc[12] = {};

  stage(0, 0);
  __syncthreads();

  for (int kc = 0; kc < NKT; ++kc) {
    const int cur = kc & 1;
    if (kc + 1 < NKT) stage(kc + 1, cur ^ 1);

    // S = Q K^T (16q x 32k per wave)
    floatx4 s0 = {0.f, 0.f, 0.f, 0.f}, s1 = {0.f, 0.f, 0.f, 0.f};
#pragma unroll
    for (int c6 = 0; c6 < 6; ++c6) {
      short8 k0f = *(const short8*)(&Kb[cur][(c6 * 64 + quad * 16 + lm) * 8]);
      short8 k1f = *(const short8*)(&Kb[cur][((6 + c6) * 64 + quad * 16 + lm) * 8]);
      s0 = __builtin_amdgcn_mfma_f32_16x16x32_bf16(qf[c6], k0f, s0, 0, 0, 0);
      s1 = __builtin_amdgcn_mfma_f32_16x16x32_bf16(qf[c6], k1f, s1, 0, 0, 0);
    }

    // online softmax update (per q-row r2; stats uniform across lm via shfl)
    float al[4];
#pragma unroll
    for (int r2 = 0; r2 < 4; ++r2) {
      float a = s0[r2] * 0.07216878364870323f;
      float c = s1[r2] * 0.07216878364870323f;
      float t = fmaxf(a, c);
#pragma unroll
      for (int off = 1; off < 16; off <<= 1) t = fmaxf(t, __shfl_xor(t, off, 64));
      float mn = fmaxf(m_r[r2], t);
      al[r2] = __expf(m_r[r2] - mn);
      m_r[r2] = mn;
      float e0 = __expf(a - mn), e1 = __expf(c - mn);
      l_r[r2] = al[r2] * l_r[r2] + e0 + e1;
      Pb[wave][(quad * 4 + r2) * 40 + lm]      = f2b(e0);
      Pb[wave][(quad * 4 + r2) * 40 + 16 + lm] = f2b(e1);
    }
#pragma unroll
    for (int dt = 0; dt < 12; ++dt) {
#pragma unroll
      for (int r2 = 0; r2 < 4; ++r2) oacc[dt][r2] *= al[r2];
    }

    // O += P @ V (P via LDS transpose to A-layout; V frag-major in LDS)
    short8 pf = *(const short8*)(&Pb[wave][lm * 40 + quad * 8]);
#pragma unroll
    for (int dt = 0; dt < 12; ++dt) {
      short8 vf = *(const short8*)(&Vb[cur][(dt * 64 + quad * 16 + lm) * 8]);
      oacc[dt] = __builtin_amdgcn_mfma_f32_16x16x32_bf16(pf, vf, oacc[dt], 0, 0, 0);
    }
    __syncthreads();
  }

  // finalize: reduce l across the 16-lane group, normalize, store bf16
#pragma unroll
  for (int r2 = 0; r2 < 4; ++r2) {
#pragma unroll
    for (int off = 1; off < 16; off <<= 1) l_r[r2] += __shfl_xor(l_r[r2], off, 64);
    l_r[r2] = 1.f / l_r[r2];
  }
  short* orow = o + (size_t)(b * T + q0 + wave * 16) * H_ + h * DH_;
#pragma unroll
  for (int dt = 0; dt < 12; ++dt) {
#pragma unroll
    for (int r2 = 0; r2 < 4; ++r2)
      orow[(size_t)(quad * 4 + r2) * H_ + dt * 16 + lm] = f2b(oacc[dt][r2] * l_r[r2]);
  }
}

// ============ LayerNorm (H=384), wave per row ============
__global__ __launch_bounds__(256) void ln_kernel(const float* __restrict__ X,
                                                 const float* __restrict__ sb,
                                                 float* __restrict__ Yf,
                                                 short* __restrict__ Yb, int M)
{
  int row  = blockIdx.x * 4 + (threadIdx.x >> 6);
  int lane = threadIdx.x & 63;
  const float* x = X + (size_t)row * H_;
  float v[6]; float s = 0.f, ss = 0.f;
#pragma unroll
  for (int i = 0; i < 6; ++i) { v[i] = x[lane + i * 64]; s += v[i]; ss += v[i] * v[i]; }
#pragma unroll
  for (int o = 32; o; o >>= 1) { s += __shfl_down(s, o, 64); ss += __shfl_down(ss, o, 64); }
  s = __shfl(s, 0, 64); ss = __shfl(ss, 0, 64);
  float mean = s * (1.0f / H_);
  float var  = ss * (1.0f / H_) - mean * mean;
  float r = rsqrtf(var + 1e-5f);
  float* yf = Yf + (size_t)row * H_;
#pragma unroll
  for (int i = 0; i < 6; ++i) {
    int c = lane + i * 64;
    float y = (v[i] - mean) * r * sb[c] + sb[H_ + c];
    yf[c] = y;
    if (Yb) Yb[(size_t)row * H_ + c] = f2b(y);
  }
}

// ============ length-pred GEMV ============
__global__ void gemv_kernel(const float* __restrict__ A, const float* __restrict__ w,
                            const float* __restrict__ bflt, float* __restrict__ out, int M)
{
  int row  = blockIdx.x * 4 + (threadIdx.x >> 6);
  int lane = threadIdx.x & 63;
  const float* a = A + (size_t)row * H_;
  float s = 0.f;
#pragma unroll
  for (int i = 0; i < 6; ++i) s += a[lane + i * 64] * w[lane + i * 64];
#pragma unroll
  for (int o = 32; o; o >>= 1) s += __shfl_down(s, o, 64);
  if (lane == 0) out[row] = s + bflt[0];
}

__global__ void cumsum_kernel(const int* __restrict__ al, int* __restrict__ cum) {
  int b = threadIdx.x;
  if (b < B_) {
    int acc = 0;
    for (int s = 0; s < S_; ++s) { acc += al[b * S_ + s]; cum[b * S_ + s] = acc; }
  }
}

__global__ void expand_kernel(const float* __restrict__ xe, const int* __restrict__ cum,
                              float* __restrict__ yf, short* __restrict__ yb) {
  int t = blockIdx.x, b = blockIdx.y;
  const int* c = cum + b * S_;
  int lo = 0, hi = S_;
  while (lo < hi) { int mid = (lo + hi) >> 1; if (c[mid] <= t) lo = mid + 1; else hi = mid; }
  int idx = lo < S_ ? lo : S_ - 1;
  bool valid = t < c[S_ - 1];
  const float* src = xe + ((size_t)b * S_ + idx) * H_;
  float* df = yf + ((size_t)b * TOUT_ + t) * H_;
  short* db = yb + ((size_t)b * TOUT_ + t) * H_;
  for (int i = threadIdx.x; i < H_; i += blockDim.x) {
    float v = (valid ? src[i] : 0.f) + pe_val(t, i);
    df[i] = v; db[i] = f2b(v);
  }
}

// ================= host orchestration =================
static inline void gemm(const short* A, const short* Wt, const float* bias, const float* res,
                        float* Cf, short* Cb, const short* zbuf, int M, int N, int Kd, int T,
                        int ntaps, int Nout, int flags, hipStream_t st) {
  dim3 g(N / 128, M / 128);
  if (ntaps == 3)
    mfma_gemm<3><<<g, 256, 0, st>>>(A, Wt, bias, res, Cf, Cb, zbuf, M, N, Kd, T, Nout, flags);
  else
    mfma_gemm<1><<<g, 256, 0, st>>>(A, Wt, bias, res, Cf, Cb, zbuf, M, N, Kd, T, Nout, flags);
}

struct LayerW { const short *attn, *c1, *c2; const float *ab, *c1b, *c2b, *ln; };

static void fft_block(float* x, short* xb, short* qkvb, short* ob, short* vtb, short* h2b,
                      const short* zbuf, const LayerW& w, int T, hipStream_t st)
{
  int M = B_ * T;
  const size_t msz = (size_t)H_ * H_;
  gemm(xb, w.attn, w.ab, nullptr, nullptr, qkvb, zbuf, M, 1152, H_, T, 1, 0, F_BIAS | F_STB, st);
  vtrans_kernel<<<dim3(T / 32, 12, B_), 256, 0, st>>>(qkvb, vtb, T);
  if (T == 256) attn_flash<256><<<dim3((256 / 64) * 32), 256, 0, st>>>(qkvb, vtb, ob);
  else          attn_flash<1024><<<dim3((1024 / 64) * 32), 256, 0, st>>>(qkvb, vtb, ob);
  gemm(ob, w.attn + 3 * msz, w.ab + 3 * H_, x, x, nullptr, zbuf, M, H_, H_, T, 1, 0,
       F_BIAS | F_RES | F_STF, st);
  ln_kernel<<<M / 4, 256, 0, st>>>(x, w.ln, x, xb, M);
  gemm(xb, w.c1, w.c1b, nullptr, nullptr, h2b, zbuf, M, H2_, H_, T, 3, 0,
       F_BIAS | F_RELU | F_STB, st);
  gemm(h2b, w.c2, w.c2b, x, x, nullptr, zbuf, M, H_, H2_, T, 3, 0, F_BIAS | F_RES | F_STF, st);
  ln_kernel<<<M / 4, 256, 0, st>>>(x, w.ln + 2 * H_, x, xb, M);
}

extern "C" void kernel_launch(void* const* d_in, const int* in_sizes, int n_in,
                              void* d_out, int out_size, void* d_ws, size_t ws_size,
                              hipStream_t stream)
{
  (void)in_sizes; (void)n_in; (void)out_size; (void)ws_size;
  const int*   tokens      = (const int*)d_in[0];
  const int*   alignes     = (const int*)d_in[1];
  const float* tok_emb     = (const float*)d_in[2];
  const float* enc_attn_w  = (const float*)d_in[3];
  const float* enc_attn_b  = (const float*)d_in[4];
  const float* enc_conv1_w = (const float*)d_in[5];
  const float* enc_conv1_b = (const float*)d_in[6];
  const float* enc_conv2_w = (const float*)d_in[7];
  const float* enc_conv2_b = (const float*)d_in[8];
  const float* enc_ln      = (const float*)d_in[9];
  const float* dec_attn_w  = (const float*)d_in[10];
  const float* dec_attn_b  = (const float*)d_in[11];
  const float* dec_conv1_w = (const float*)d_in[12];
  const float* dec_conv1_b = (const float*)d_in[13];
  const float* dec_conv2_w = (const float*)d_in[14];
  const float* dec_conv2_b = (const float*)d_in[15];
  const float* dec_ln      = (const float*)d_in[16];
  const float* al_c1w      = (const float*)d_in[17];
  const float* al_c1b      = (const float*)d_in[18];
  const float* al_c2w      = (const float*)d_in[19];
  const float* al_c2b      = (const float*)d_in[20];
  const float* al_ln       = (const float*)d_in[21];
  const float* al_lin_w    = (const float*)d_in[22];
  const float* al_lin_b    = (const float*)d_in[23];
  const float* dec_lin_w   = (const float*)d_in[24];
  const float* dec_lin_b   = (const float*)d_in[25];

  char* base = (char*)d_ws;
  size_t off = 0;
  auto alloc = [&](size_t bytes) -> char* {
    char* p = base + off;
    off += (bytes + 255) & ~(size_t)255;
    return p;
  };
  const size_t ME = (size_t)B_ * S_;      // 4096
  const size_t MD = (size_t)B_ * TOUT_;   // 16384
  float* xe   = (float*)alloc(ME * H_ * 4);
  short* xeb  = (short*)alloc(ME * H_ * 2);
  float* xd   = (float*)alloc(MD * H_ * 4);
  short* xdb  = (short*)alloc(MD * H_ * 2);
  short* qkvb = (short*)alloc(MD * 1152 * 2);
  short* ob   = (short*)alloc(MD * H_ * 2);
  short* h2b  = (short*)alloc(MD * H2_ * 2);     // first 12.6MB doubles as vtb
  short* vtb  = h2b;
  short* wAt  = (short*)alloc((size_t)32 * H_ * H_ * 2);
  short* wAl  = (short*)alloc((size_t)6 * H_ * H_ * 2);
  short* wC1  = (short*)alloc((size_t)24 * H_ * H2_ * 2);
  short* wC2  = (short*)alloc((size_t)24 * H_ * H2_ * 2);
  short* wMel = (short*)alloc((size_t)128 * H_ * 2);
  int*   cum  = (int*)alloc(ME * 4);
  short* zbuf = (short*)alloc(256);
  float* alf  = xd;                // aligner scratch (xd/xdb free until expand)
  short* alb  = xdb;

  float* mel_out = (float*)d_out;
  float* len_out = mel_out + (size_t)B_ * MEL_ * TOUT_;

  hipMemsetAsync(zbuf, 0, 256, stream);

  // ---- weight prep ----
  wtrans_kernel<<<dim3(12, 12, 32), 256, 0, stream>>>(enc_attn_w, dec_attn_w, 16, H_, H_, wAt);
  wtrans_kernel<<<dim3(12, 12, 6),  256, 0, stream>>>(al_c1w, al_c2w, 3, H_, H_, wAl);
  wtrans_kernel<<<dim3(48, 12, 24), 256, 0, stream>>>(enc_conv1_w, dec_conv1_w, 12, H_, H2_, wC1);
  wtrans_kernel<<<dim3(12, 48, 24), 256, 0, stream>>>(enc_conv2_w, dec_conv2_w, 12, H2_, H_, wC2);
  melpad_kernel<<<dim3(128 * H_ / 256), 256, 0, stream>>>(dec_lin_w, wMel);

  // ---- encoder ----
  embed_kernel<<<dim3(B_ * S_), 128, 0, stream>>>(tokens, tok_emb, xe, xeb);
  for (int i = 0; i < L_; ++i) {
    LayerW w;
    w.attn = wAt + (size_t)i * 4 * H_ * H_;
    w.c1   = wC1 + (size_t)i * 3 * H_ * H2_;
    w.c2   = wC2 + (size_t)i * 3 * H_ * H2_;
    w.ab   = enc_attn_b + (size_t)i * 4 * H_;
    w.c1b  = enc_conv1_b + (size_t)i * H2_;
    w.c2b  = enc_conv2_b + (size_t)i * H_;
    w.ln   = enc_ln + (size_t)i * 4 * H_;
    fft_block(xe, xeb, qkvb, ob, vtb, h2b, zbuf, w, S_, stream);
  }

  // ---- aligner ----
  {
    int Ma = B_ * S_;
    gemm(xeb, wAl, al_c1b, nullptr, alf, nullptr, zbuf, Ma, H_, H_, S_, 3, 0,
         F_BIAS | F_RELU | F_STF, stream);
    ln_kernel<<<Ma / 4, 256, 0, stream>>>(alf, al_ln, alf, alb, Ma);
    gemm(alb, wAl + (size_t)3 * H_ * H_, al_c2b, nullptr, alf, nullptr, zbuf, Ma, H_, H_, S_,
         3, 0, F_BIAS | F_RELU | F_STF, stream);
    ln_kernel<<<Ma / 4, 256, 0, stream>>>(alf, al_ln + 2 * H_, alf, (short*)nullptr, Ma);
    gemv_kernel<<<Ma / 4, 256, 0, stream>>>(alf, al_lin_w, al_lin_b, len_out, Ma);
  }

  // ---- length regulator ----
  cumsum_kernel<<<1, 64, 0, stream>>>(alignes, cum);
  expand_kernel<<<dim3(TOUT_, B_), 128, 0, stream>>>(xe, cum, xd, xdb);

  // ---- decoder ----
  for (int i = 0; i < L_; ++i) {
    LayerW w;
    w.attn = wAt + (size_t)(16 + i * 4) * H_ * H_;
    w.c1   = wC1 + (size_t)(12 + i * 3) * H_ * H2_;
    w.c2   = wC2 + (size_t)(12 + i * 3) * H_ * H2_;
    w.ab   = dec_attn_b + (size_t)i * 4 * H_;
    w.c1b  = dec_conv1_b + (size_t)i * H2_;
    w.c2b  = dec_conv2_b + (size_t)i * H_;
    w.ln   = dec_ln + (size_t)i * 4 * H_;
    fft_block(xd, xdb, qkvb, ob, vtb, h2b, zbuf, w, TOUT_, stream);
  }

  // ---- final mel projection, transposed write [B, MEL, TOUT] ----
  gemm(xdb, wMel, dec_lin_b, nullptr, mel_out, nullptr, zbuf, B_ * TOUT_, 128, H_, TOUT_,
       1, MEL_, F_BIAS | F_TRANS, stream);
}